// Round 10
// baseline (290.923 us; speedup 1.0000x reference)
//
#include <hip/hip_runtime.h>
#include <hip/hip_fp16.h>
#include <math.h>

#define EPSV 1e-5
#define SLOPE 0.1f

typedef __attribute__((ext_vector_type(4))) float f32x4;
typedef __attribute__((ext_vector_type(8))) short short8x;

__device__ __forceinline__ float lrelu(float x){ return x >= 0.f ? x : SLOPE * x; }
__device__ __forceinline__ float tanh_fast(float x){
  float e = __expf(2.f * x);
  return 1.f - 2.f / (e + 1.f);
}
__device__ __forceinline__ unsigned bf16rne(float f){
  unsigned u = __float_as_uint(f);
  u += 0x7fff + ((u >> 16) & 1);
  return u >> 16;
}

// ---- block BN-stats epilogue: per-thread CL channel sums/sqs -> f64 partials (padded stride) ----
template<int CL>
__device__ __forceinline__ void stats_epilogue(const float* sums, const float* sqs,
    double* __restrict__ part, int chbase, int P, int p, float* sred){
  const int C2 = 2 * CL;
  const int ST = C2 + 1;            // pad to break power-of-2 bank stride
  int t = threadIdx.x;
  #pragma unroll
  for (int c = 0; c < CL; c++){
    sred[t * ST + c] = sums[c];
    sred[t * ST + CL + c] = sqs[c];
  }
  __syncthreads();
  if (t < 64){
    int c = t % C2;
    int g = t / C2;
    const int G = 64 / C2;
    const int R = 256 / G;
    double s = 0;
    for (int r = g * R; r < (g + 1) * R; r++) s += (double)sred[r * ST + c];
    #pragma unroll
    for (int off = C2; off < 64; off <<= 1) s += __shfl_xor(s, off);
    if (t < C2){
      int ch = chbase + (c < CL ? c : c - CL);
      part[(size_t)ch * 2 * P + (c < CL ? 0 : P) + p] = s;
    }
  }
}

// ---- reduce partials + finalize scale/shift ----
__global__ __launch_bounds__(256) void bn_red_fin(const double* __restrict__ part, int P,
    const float* __restrict__ g, const float* __restrict__ b, float* __restrict__ ss, int C, double count){
  int c = blockIdx.x;
  __shared__ double r0[256], r1[256];
  int t = threadIdx.x;
  double s = 0, q = 0;
  for (int p = t; p < P; p += 256){
    s += part[(size_t)c * 2 * P + p];
    q += part[(size_t)c * 2 * P + P + p];
  }
  r0[t] = s; r1[t] = q; __syncthreads();
  for (int o = 128; o > 0; o >>= 1){
    if (t < o){ r0[t] += r0[t + o]; r1[t] += r1[t + o]; }
    __syncthreads();
  }
  if (t == 0){
    double m = r0[0] / count;
    double var = r1[0] / count - m * m;
    double scale = (double)g[c] / sqrt(var + EPSV);
    ss[c] = (float)scale;
    ss[C + c] = (float)((double)b[c] - m * scale);
  }
}

// ---------------- e1: 3->16 s2, co-split x2 (8 co/thread), 2 x-outputs, fused bn1-stats ----------------
__global__ __launch_bounds__(256) void e1_conv(const float* __restrict__ x, const float* __restrict__ w,
    const float* __restrict__ bias, float* __restrict__ out, double* __restrict__ part){
  int idx = blockIdx.x * 256 + threadIdx.x;
  int ox2 = idx & 63, oy = (idx >> 6) & 127;
  int cog = (idx >> 13) & 1, n = idx >> 14;
  cog = __builtin_amdgcn_readfirstlane(cog);
  n   = __builtin_amdgcn_readfirstlane(n);
  float acc[8][2];
  #pragma unroll
  for (int co = 0; co < 8; co++){ float b = bias[cog * 8 + co]; acc[co][0] = b; acc[co][1] = b; }
  int ix0 = 4 * ox2 - 1;
  int lclamp = (ox2 > 0) ? ix0 : 0;
  const float* xp = x + (size_t)n * 3 * 65536;
  #pragma unroll
  for (int ci = 0; ci < 3; ci++){
    const float* pl = xp + ci * 65536;
    #pragma unroll
    for (int ky = 0; ky < 3; ky++){
      int iy = 2 * oy - 1 + ky;
      if (iy >= 0){
        const float* row = pl + iy * 256;
        float l = row[lclamp];
        float4 m = *(const float4*)(row + ix0 + 1);
        float v0 = (ox2 > 0) ? l : 0.f;
        #pragma unroll
        for (int co = 0; co < 8; co++){
          const float* wp = w + (((cog * 8 + co) * 3 + ci) * 3 + ky) * 3;
          acc[co][0] = fmaf(v0,  wp[0], acc[co][0]);
          acc[co][0] = fmaf(m.x, wp[1], acc[co][0]);
          acc[co][0] = fmaf(m.y, wp[2], acc[co][0]);
          acc[co][1] = fmaf(m.y, wp[0], acc[co][1]);
          acc[co][1] = fmaf(m.z, wp[1], acc[co][1]);
          acc[co][1] = fmaf(m.w, wp[2], acc[co][1]);
        }
      }
    }
  }
  float sums[8], sqs[8];
  #pragma unroll
  for (int co = 0; co < 8; co++){
    float2 st; st.x = acc[co][0]; st.y = acc[co][1];
    *(float2*)(out + ((size_t)(n * 16 + cog * 8 + co) * 128 + oy) * 128 + 2 * ox2) = st;
    sums[co] = acc[co][0] + acc[co][1];
    sqs[co] = acc[co][0] * acc[co][0] + acc[co][1] * acc[co][1];
  }
  __shared__ float sred[256 * 17];
  int p = ((blockIdx.x >> 6) << 5) + (blockIdx.x & 31);
  stats_epilogue<8>(sums, sqs, part, cog * 8, 512, p, sred);
}

// ---------------- e2: 16->4 s2 with fused bn1-apply on loads + bn2-stats ----------------
__global__ __launch_bounds__(256) void e2_conv(const float* __restrict__ in, const float* __restrict__ w,
    const float* __restrict__ bias, const float* __restrict__ ssIn, float* __restrict__ out,
    double* __restrict__ part){
  int idx = blockIdx.x * 256 + threadIdx.x;
  int ox = idx & 63, oy = (idx >> 6) & 63, n = idx >> 12;
  float acc[4];
  #pragma unroll
  for (int j = 0; j < 4; j++) acc[j] = bias[j];
  int iy0 = oy * 2 - 1, ix0 = ox * 2 - 1;
  const float* ip = in + (size_t)n * 16 * 16384;
  #pragma unroll
  for (int ky = 0; ky < 3; ky++){
    int iy = iy0 + ky; if ((unsigned)iy >= 128u) continue;
    #pragma unroll
    for (int kx = 0; kx < 3; kx++){
      int ix = ix0 + kx; if ((unsigned)ix >= 128u) continue;
      const float* r = ip + iy * 128 + ix;
      #pragma unroll
      for (int ci = 0; ci < 16; ci++){
        float v = lrelu(fmaf(r[ci * 16384], ssIn[ci], ssIn[16 + ci]));
        #pragma unroll
        for (int co = 0; co < 4; co++)
          acc[co] = fmaf(v, w[(co * 16 + ci) * 9 + ky * 3 + kx], acc[co]);
      }
    }
  }
  float sums[4], sqs[4];
  #pragma unroll
  for (int co = 0; co < 4; co++){
    out[(((size_t)n * 4 + co) * 64 + oy) * 64 + ox] = acc[co];
    sums[co] = acc[co];
    sqs[co] = acc[co] * acc[co];
  }
  __shared__ float sred[256 * 9];
  stats_epilogue<4>(sums, sqs, part, 0, 256, blockIdx.x, sred);
}

// ---------------- preq: fused bn2-apply, output plane layout Zq[coq][pos][4] ----------------
__global__ __launch_bounds__(256) void preq_conv(const float* __restrict__ in, const float* __restrict__ w,
    const float* __restrict__ bias, const float* __restrict__ ssIn, float* __restrict__ Zq){
  int idx = blockIdx.x * 256 + threadIdx.x;
  int sp = idx & 65535;
  int coq = idx >> 16;
  int x = sp & 63, y = (sp >> 6) & 63, n = sp >> 12;
  float scv[4] = {ssIn[0], ssIn[1], ssIn[2], ssIn[3]};
  float shv[4] = {ssIn[4], ssIn[5], ssIn[6], ssIn[7]};
  float a0 = bias[coq * 4 + 0], a1 = bias[coq * 4 + 1], a2 = bias[coq * 4 + 2], a3 = bias[coq * 4 + 3];
  const float* ip = in + (size_t)n * 4 * 4096;
  #pragma unroll
  for (int ky = 0; ky < 3; ky++){
    int iy = y - 1 + ky; if ((unsigned)iy >= 64u) continue;
    #pragma unroll
    for (int kx = 0; kx < 3; kx++){
      int ix = x - 1 + kx; if ((unsigned)ix >= 64u) continue;
      #pragma unroll
      for (int ci = 0; ci < 4; ci++){
        float v = lrelu(fmaf(ip[ci * 4096 + iy * 64 + ix], scv[ci], shv[ci]));
        const float* wp = w + ((coq * 4) * 4 + ci) * 9 + ky * 3 + kx;
        a0 = fmaf(v, wp[0], a0);
        a1 = fmaf(v, wp[36], a1);
        a2 = fmaf(v, wp[72], a2);
        a3 = fmaf(v, wp[108], a3);
      }
    }
  }
  float4 o; o.x = a0; o.y = a1; o.z = a2; o.w = a3;
  ((float4*)Zq)[coq * 65536 + sp] = o;
}

// ---------------- prep_all: blocks 0-3 VQ codebook prep, blocks 4-39 postq P-table ----------------
__global__ __launch_bounds__(256) void prep_all(const float* __restrict__ cb, double* __restrict__ cb64,
    double* __restrict__ cbn64, float* __restrict__ cbn32, unsigned short* __restrict__ cbh,
    unsigned short* __restrict__ cbl, int* __restrict__ flagcnt,
    const float* __restrict__ pw, float* __restrict__ P){
  int t = threadIdx.x;
  if (blockIdx.x < 4){
    int k = blockIdx.x * 256 + t;
    if (k == 0) flagcnt[0] = 0;
    double s = 0;
    for (int d = 0; d < 64; d++){
      float v = cb[k * 64 + d];
      cb64[(size_t)k * 64 + d] = (double)v;
      s = fma((double)v, (double)v, s);
      unsigned h = bf16rne(v);
      float hf = __uint_as_float(h << 16);
      unsigned l = bf16rne(v - hf);
      cbh[k * 64 + d] = (unsigned short)h;
      cbl[k * 64 + d] = (unsigned short)l;
    }
    cbn64[k] = s;
    cbn32[k] = (float)s;
  } else {
    int gid = (blockIdx.x - 4) * 256 + t;
    if (gid >= 9216) return;
    int k = gid / 9, tap = gid - k * 9;
    float a0 = 0.f, a1 = 0.f, a2 = 0.f, a3 = 0.f;
    const float* cp = cb + (k << 6);
    #pragma unroll 16
    for (int ci = 0; ci < 64; ci++){
      float c = cp[ci];
      a0 = fmaf(c, pw[(0 * 64 + ci) * 9 + tap], a0);
      a1 = fmaf(c, pw[(1 * 64 + ci) * 9 + tap], a1);
      a2 = fmaf(c, pw[(2 * 64 + ci) * 9 + tap], a2);
      a3 = fmaf(c, pw[(3 * 64 + ci) * 9 + tap], a3);
    }
    float4 o; o.x = a0; o.y = a1; o.z = a2; o.w = a3;
    ((float4*)P)[gid] = o;
  }
}

// ---------------- VQ screen via MFMA: per-step (128-code) partial bests + global merge ----------------
__global__ __launch_bounds__(256) void vq_screen_mfma(const float* __restrict__ Zq,
    const unsigned short* __restrict__ cbh, const unsigned short* __restrict__ cbl,
    const float* __restrict__ cbn32, int* __restrict__ idxout,
    int* __restrict__ flagcnt, int* __restrict__ flaglist, float* __restrict__ stepb){
  __shared__ unsigned short lcb[32 * 64 * 8];
  __shared__ float lcn[128];
  int t = threadIdx.x;
  int lane = t & 63;
  int w = t >> 6;
  int col = lane & 15, hg = lane >> 4;
  int pos0 = blockIdx.x * 128 + w * 32;
  int posA = pos0 + col, posB = pos0 + 16 + col;
  const float4* Zq4 = (const float4*)Zq;
  short8x zhA[2], zlA[2], zhB[2], zlB[2];
  #pragma unroll
  for (int kc = 0; kc < 2; kc++){
    #pragma unroll
    for (int tb = 0; tb < 2; tb++){
      int pos = tb ? posB : posA;
      float4 f0 = Zq4[(size_t)(8 * kc + 2 * hg) * 65536 + pos];
      float4 f1 = Zq4[(size_t)(8 * kc + 2 * hg + 1) * 65536 + pos];
      float zv[8] = {f0.x, f0.y, f0.z, f0.w, f1.x, f1.y, f1.z, f1.w};
      union { unsigned u[4]; short8x v; } H, L;
      #pragma unroll
      for (int j = 0; j < 4; j++){
        unsigned h0 = bf16rne(zv[2 * j]);
        unsigned h1 = bf16rne(zv[2 * j + 1]);
        float hf0 = __uint_as_float(h0 << 16);
        float hf1 = __uint_as_float(h1 << 16);
        unsigned l0 = bf16rne(zv[2 * j] - hf0);
        unsigned l1 = bf16rne(zv[2 * j + 1] - hf1);
        H.u[j] = h0 | (h1 << 16);
        L.u[j] = l0 | (l1 << 16);
      }
      if (tb){ zhB[kc] = H.v; zlB[kc] = L.v; } else { zhA[kc] = H.v; zlA[kc] = L.v; }
    }
  }
  float BA = 3.0e38f, SA = 3.0e38f, BB = 3.0e38f, SBt = 3.0e38f;
  int IA = 0, IB = 0;
  for (int step = 0; step < 8; step++){
    int code0 = step * 128;
    __syncthreads();
    #pragma unroll
    for (int i = 0; i < 8; i++){
      int piece = i * 256 + t;
      int fb = piece >> 6, pl = piece & 63;
      int g = fb >> 2, kc = (fb >> 1) & 1, sp = fb & 1;
      const unsigned short* src = (sp ? cbl : cbh)
          + ((size_t)(code0 + g * 16 + (pl & 15)) << 6) + kc * 32 + ((pl >> 4) << 3);
      *(uint4*)&lcb[piece * 8] = *(const uint4*)src;
    }
    if (t < 128) lcn[t] = cbn32[code0 + t];
    __syncthreads();
    float bA = 3.0e38f, sA = 3.0e38f, bB = 3.0e38f, sB = 3.0e38f;
    int iA = 0, iB = 0;
    #pragma unroll 2
    for (int g = 0; g < 8; g++){
      const short8x* lc8 = (const short8x*)lcb;
      short8x Ah0 = lc8[(g * 4 + 0) * 64 + lane];
      short8x Al0 = lc8[(g * 4 + 1) * 64 + lane];
      short8x Ah1 = lc8[(g * 4 + 2) * 64 + lane];
      short8x Al1 = lc8[(g * 4 + 3) * 64 + lane];
      f32x4 accA = {0.f, 0.f, 0.f, 0.f};
      f32x4 accB = {0.f, 0.f, 0.f, 0.f};
      accA = __builtin_amdgcn_mfma_f32_16x16x32_bf16(Ah0, zhA[0], accA, 0, 0, 0);
      accA = __builtin_amdgcn_mfma_f32_16x16x32_bf16(Ah1, zhA[1], accA, 0, 0, 0);
      accA = __builtin_amdgcn_mfma_f32_16x16x32_bf16(Ah0, zlA[0], accA, 0, 0, 0);
      accA = __builtin_amdgcn_mfma_f32_16x16x32_bf16(Ah1, zlA[1], accA, 0, 0, 0);
      accA = __builtin_amdgcn_mfma_f32_16x16x32_bf16(Al0, zhA[0], accA, 0, 0, 0);
      accA = __builtin_amdgcn_mfma_f32_16x16x32_bf16(Al1, zhA[1], accA, 0, 0, 0);
      accB = __builtin_amdgcn_mfma_f32_16x16x32_bf16(Ah0, zhB[0], accB, 0, 0, 0);
      accB = __builtin_amdgcn_mfma_f32_16x16x32_bf16(Ah1, zhB[1], accB, 0, 0, 0);
      accB = __builtin_amdgcn_mfma_f32_16x16x32_bf16(Ah0, zlB[0], accB, 0, 0, 0);
      accB = __builtin_amdgcn_mfma_f32_16x16x32_bf16(Ah1, zlB[1], accB, 0, 0, 0);
      accB = __builtin_amdgcn_mfma_f32_16x16x32_bf16(Al0, zhB[0], accB, 0, 0, 0);
      accB = __builtin_amdgcn_mfma_f32_16x16x32_bf16(Al1, zhB[1], accB, 0, 0, 0);
      int cbase = code0 + g * 16 + 4 * hg;
      #pragma unroll
      for (int r = 0; r < 4; r++){
        float cn = lcn[g * 16 + 4 * hg + r];
        float vA = fmaf(accA[r], -2.0f, cn);
        sA = fminf(sA, fmaxf(vA, bA));
        if (vA < bA){ bA = vA; iA = cbase + r; }
        float vB = fmaf(accB[r], -2.0f, cn);
        sB = fminf(sB, fmaxf(vB, bB));
        if (vB < bB){ bB = vB; iB = cbase + r; }
      }
    }
    #pragma unroll
    for (int off = 16; off <= 32; off <<= 1){
      float ob = __shfl_xor(bA, off);
      float os = __shfl_xor(sA, off);
      int oi = __shfl_xor(iA, off);
      sA = fminf(fminf(sA, os), fmaxf(bA, ob));
      if (ob < bA){ bA = ob; iA = oi; }
      ob = __shfl_xor(bB, off);
      os = __shfl_xor(sB, off);
      oi = __shfl_xor(iB, off);
      sB = fminf(fminf(sB, os), fmaxf(bB, ob));
      if (ob < bB){ bB = ob; iB = oi; }
    }
    if (hg == 0){
      stepb[step * 65536 + posA] = bA;
      stepb[step * 65536 + posB] = bB;
    }
    if (bA < BA){ SA = fminf(BA, sA); BA = bA; IA = iA; } else SA = fminf(SA, bA);
    if (bB < BB){ SBt = fminf(BB, sB); BB = bB; IB = iB; } else SBt = fminf(SBt, bB);
  }
  if (hg == 0){
    idxout[posA] = IA;
    if (SA - BA < 1.2e-2f){
      int slot = atomicAdd(flagcnt, 1);
      flaglist[slot] = posA;
    }
    idxout[posB] = IB;
    if (SBt - BB < 1.2e-2f){
      int slot = atomicAdd(flagcnt, 1);
      flaglist[slot] = posB;
    }
  }
}

// ---------------- VQ refine: exact f64 re-rank over candidate steps only ----------------
__global__ __launch_bounds__(256) void vq_refine(const float* __restrict__ Zq, const double* __restrict__ cb64,
    const double* __restrict__ cbn64, const int* __restrict__ flagcnt, const int* __restrict__ flaglist,
    const float* __restrict__ stepb, int* __restrict__ idxout){
  int gw = (blockIdx.x * 256 + threadIdx.x) >> 6;
  int lane = threadIdx.x & 63;
  int nf = flagcnt[0];
  for (int f = gw; f < nf; f += 512){
    int pos = flaglist[f];
    float zr[64];
    #pragma unroll
    for (int q = 0; q < 16; q++){
      float4 v = ((const float4*)Zq)[q * 65536 + pos];
      zr[4 * q] = v.x; zr[4 * q + 1] = v.y; zr[4 * q + 2] = v.z; zr[4 * q + 3] = v.w;
    }
    float sb[8];
    float B = 3.0e38f;
    #pragma unroll
    for (int s = 0; s < 8; s++){ sb[s] = stepb[s * 65536 + pos]; B = fminf(B, sb[s]); }
    float lim = B + 1.2e-2f;
    double best = 1e300; int bi = 1 << 30;
    #pragma unroll
    for (int s = 0; s < 8; s++){
      if (sb[s] < lim){
        int k0 = s * 128 + 2 * lane;
        #pragma unroll
        for (int kk = 0; kk < 2; kk++){
          int k = k0 + kk;
          const double* c = cb64 + (size_t)k * 64;
          double a0 = 0, a1 = 0, a2 = 0, a3 = 0;
          #pragma unroll
          for (int d = 0; d < 64; d += 4){
            a0 = fma(c[d], (double)zr[d], a0);
            a1 = fma(c[d + 1], (double)zr[d + 1], a1);
            a2 = fma(c[d + 2], (double)zr[d + 2], a2);
            a3 = fma(c[d + 3], (double)zr[d + 3], a3);
          }
          double sc = cbn64[k] - 2.0 * ((a0 + a1) + (a2 + a3));
          if (sc < best){ best = sc; bi = k; }
        }
      }
    }
    #pragma unroll
    for (int o = 32; o > 0; o >>= 1){
      double ob = __shfl_xor(best, o);
      int oi = __shfl_xor(bi, o);
      if (ob < best || (ob == best && oi < bi)){ best = ob; bi = oi; }
    }
    if (lane == 0) idxout[pos] = bi;
  }
}

// ---------------- postq gather: out[pos][co] = bias + sum_tap P[idx[nbr]][tap][co]; fused loss ----------------
__global__ __launch_bounds__(256) void postq_gather(const float* __restrict__ P, const int* __restrict__ idxm,
    const float* __restrict__ bias, float* __restrict__ out,
    const float* __restrict__ Zq, const float* __restrict__ cb, double* __restrict__ losspart){
  int gid = blockIdx.x * 256 + threadIdx.x;
  int sp = gid & 65535;
  int co = gid >> 16;
  co = __builtin_amdgcn_readfirstlane(co);
  int xx = sp & 63, yy = (sp >> 6) & 63, n = sp >> 12;
  float acc = bias[co];
  #pragma unroll
  for (int ky = 0; ky < 3; ky++){
    int iy = yy - 1 + ky; if ((unsigned)iy >= 64u) continue;
    #pragma unroll
    for (int kx = 0; kx < 3; kx++){
      int ix = xx - 1 + kx; if ((unsigned)ix >= 64u) continue;
      int spt = (n << 12) + (iy << 6) + ix;
      int k = idxm[spt];
      acc += P[(k * 9 + (ky * 3 + kx)) * 4 + co];
    }
  }
  out[((size_t)(n * 4 + co) << 12) + (yy << 6) + xx] = acc;
  if (co == 0){
    int k = idxm[sp];
    const float4* c4 = (const float4*)(cb + (k << 6));
    double l = 0;
    #pragma unroll
    for (int q = 0; q < 16; q++){
      float4 z = ((const float4*)Zq)[q * 65536 + sp];
      float4 c = c4[q];
      float d0 = z.x - c.x, d1 = z.y - c.y, d2 = z.z - c.z, d3 = z.w - c.w;
      l += (double)d0 * d0 + (double)d1 * d1 + (double)d2 * d2 + (double)d3 * d3;
    }
    __shared__ double sb[256];
    int t = threadIdx.x;
    sb[t] = l; __syncthreads();
    for (int o = 128; o > 0; o >>= 1){
      if (t < o) sb[t] += sb[t + o];
      __syncthreads();
    }
    if (t == 0) losspart[blockIdx.x] = sb[0];
  }
}

// ---------------- transposed conv k3 s2 p1 op1, 8 co/thread, optional input-BN, fused stats ----------------
// HOUT: store output as fp16 (half2 pairs)
template<int CI, int CO, int IHt, int IWt, bool APPLY, bool HOUT>
__global__ __launch_bounds__(256) void convT_cob8(const float* __restrict__ in, const float* __restrict__ w,
    const float* __restrict__ bias, const float* __restrict__ ssIn, float* __restrict__ out,
    double* __restrict__ part){
  constexpr int SB = IHt * IWt / 256;
  constexpr int COG = CO / 8;
  constexpr int P = 16 * SB;
  const int OW = IWt * 2;
  int idx = blockIdx.x * 256 + threadIdx.x;
  int ix = idx % IWt, iy = (idx / IWt) % IHt;
  int cog = (idx / (IWt * IHt)) % COG, n = idx / (IWt * IHt * COG);
  cog = __builtin_amdgcn_readfirstlane(cog);
  n   = __builtin_amdgcn_readfirstlane(n);
  float a00[8], a01[8], a10[8], a11[8];
  #pragma unroll
  for (int j = 0; j < 8; j++){ float b = bias[cog * 8 + j]; a00[j] = b; a01[j] = b; a10[j] = b; a11[j] = b; }
  bool okx = (ix + 1 < IWt), oky = (iy + 1 < IHt);
  int ixp = okx ? ix + 1 : ix, iyp = oky ? iy + 1 : iy;
  const float* ip = in + (size_t)n * CI * IHt * IWt;
  #pragma unroll 4
  for (int ci = 0; ci < CI; ci++){
    const float* p = ip + ci * IHt * IWt;
    float v00 = p[iy * IWt + ix];
    float v01 = p[iy * IWt + ixp];
    float v10 = p[iyp * IWt + ix];
    float v11 = p[iyp * IWt + ixp];
    if (APPLY){
      float sc = ssIn[ci], sh = ssIn[CI + ci];
      v00 = lrelu(fmaf(v00, sc, sh));
      v01 = lrelu(fmaf(v01, sc, sh));
      v10 = lrelu(fmaf(v10, sc, sh));
      v11 = lrelu(fmaf(v11, sc, sh));
    }
    if (!okx) v01 = 0.f;
    if (!oky) v10 = 0.f;
    if (!(okx && oky)) v11 = 0.f;
    const float* wp = w + ((size_t)ci * CO + cog * 8) * 9;
    #pragma unroll
    for (int j = 0; j < 8; j++){
      const float* q = wp + j * 9;
      a00[j] = fmaf(q[4], v00, a00[j]);
      a01[j] = fmaf(q[3], v01, a01[j]); a01[j] = fmaf(q[5], v00, a01[j]);
      a10[j] = fmaf(q[1], v10, a10[j]); a10[j] = fmaf(q[7], v00, a10[j]);
      a11[j] = fmaf(q[0], v11, a11[j]); a11[j] = fmaf(q[2], v10, a11[j]);
      a11[j] = fmaf(q[6], v01, a11[j]); a11[j] = fmaf(q[8], v00, a11[j]);
    }
  }
  float sums[8], sqs[8];
  #pragma unroll
  for (int j = 0; j < 8; j++){
    size_t eo = (((size_t)n * CO + cog * 8 + j) * (IHt * 2) + 2 * iy) * OW + 2 * ix;
    if (HOUT){
      __half* oh = (__half*)out;
      *(__half2*)(oh + eo) = __halves2half2(__float2half_rn(a00[j]), __float2half_rn(a01[j]));
      *(__half2*)(oh + eo + OW) = __halves2half2(__float2half_rn(a10[j]), __float2half_rn(a11[j]));
    } else {
      float2 r0; r0.x = a00[j]; r0.y = a01[j];
      float2 r1; r1.x = a10[j]; r1.y = a11[j];
      *(float2*)(out + eo) = r0;
      *(float2*)(out + eo + OW) = r1;
    }
    sums[j] = (a00[j] + a01[j]) + (a10[j] + a11[j]);
    sqs[j] = (a00[j] * a00[j] + a01[j] * a01[j]) + (a10[j] * a10[j] + a11[j] * a11[j]);
  }
  __shared__ float sred[256 * 17];
  int sb = blockIdx.x % SB;
  stats_epilogue<8>(sums, sqs, part, cog * 8, P, n * SB + sb, sred);
}

// ---------------- d3: 32->3 @256x256, LDS-tiled (24 KB), fp16 F input, fused bn4 + loss write ----------------
__global__ __launch_bounds__(256) void d3_tile(const __half* __restrict__ F, const float* __restrict__ w,
    const float* __restrict__ bias, const float* __restrict__ ss, float* __restrict__ out,
    const double* __restrict__ losspart){
  __shared__ float st[4 * 6 * 256];
  int t = threadIdx.x;
  int xg = t & 63, r = t >> 6;
  int n = blockIdx.x >> 6, oyb = blockIdx.x & 63;
  int oy = oyb * 4 + r;
  if (blockIdx.x == 0 && t < 64){
    double s = losspart[t] + losspart[t + 64] + losspart[t + 128] + losspart[t + 192];
    #pragma unroll
    for (int o = 32; o > 0; o >>= 1) s += __shfl_xor(s, o);
    if (t == 0) out[3145728] = (float)(1.25 * s / (65536.0 * 64.0));
  }
  float acc[3][4];
  #pragma unroll
  for (int co = 0; co < 3; co++){
    float b = bias[co];
    #pragma unroll
    for (int j = 0; j < 4; j++) acc[co][j] = b;
  }
  const __half* base = F + (size_t)n * 32 * 65536;
  for (int cc = 0; cc < 8; cc++){
    int cib = cc * 4;
    #pragma unroll
    for (int j = 0; j < 6; j++){
      int p = j * 256 + t;
      int cl = p / 384, rem = p - cl * 384;
      int rr = rem >> 6, xq = rem & 63;
      int g = oyb * 4 - 1 + rr;
      float4 v;
      if ((unsigned)g < 256u){
        union { uint2 u; __half2 h[2]; } U;
        U.u = *(const uint2*)(base + ((size_t)(cib + cl) * 256 + g) * 256 + 4 * xq);
        float2 fa = __half22float2(U.h[0]);
        float2 fb = __half22float2(U.h[1]);
        float sc = ss[cib + cl], sh = ss[32 + cib + cl];
        v.x = lrelu(fmaf(fa.x, sc, sh));
        v.y = lrelu(fmaf(fa.y, sc, sh));
        v.z = lrelu(fmaf(fb.x, sc, sh));
        v.w = lrelu(fmaf(fb.y, sc, sh));
      } else {
        v.x = 0.f; v.y = 0.f; v.z = 0.f; v.w = 0.f;
      }
      *(float4*)&st[((cl * 6 + rr) << 8) | (4 * xq)] = v;
    }
    __syncthreads();
    #pragma unroll
    for (int cl = 0; cl < 4; cl++){
      #pragma unroll
      for (int ky = 0; ky < 3; ky++){
        int rr = r + ky;
        float4 A = *(const float4*)&st[((cl * 6 + rr) << 8) | (4 * xg)];
        float Lv = __shfl_up(A.w, 1);
        float Rv = __shfl_down(A.x, 1);
        float u0 = (xg == 0) ? 0.f : Lv;
        float u5 = (xg == 63) ? 0.f : Rv;
        float u[6] = {u0, A.x, A.y, A.z, A.w, u5};
        #pragma unroll
        for (int co = 0; co < 3; co++){
          const float* wp = w + ((co * 32 + cib + cl) * 9) + ky * 3;
          #pragma unroll
          for (int j = 0; j < 4; j++){
            acc[co][j] = fmaf(u[j],     wp[0], acc[co][j]);
            acc[co][j] = fmaf(u[j + 1], wp[1], acc[co][j]);
            acc[co][j] = fmaf(u[j + 2], wp[2], acc[co][j]);
          }
        }
      }
    }
    __syncthreads();
  }
  #pragma unroll
  for (int co = 0; co < 3; co++){
    float4 s0;
    s0.x = tanh_fast(acc[co][0]); s0.y = tanh_fast(acc[co][1]);
    s0.z = tanh_fast(acc[co][2]); s0.w = tanh_fast(acc[co][3]);
    float* o = out + ((size_t)(n * 3 + co) * 256 + oy) * 256 + 4 * xg;
    *(float4*)o = s0;
  }
}

// ---------------- launch ----------------
extern "C" void kernel_launch(void* const* d_in, const int* in_sizes, int n_in,
                              void* d_out, int out_size, void* d_ws, size_t ws_size,
                              hipStream_t stream){
  const float* x      = (const float*)d_in[0];
  const float* cb     = (const float*)d_in[1];
  const float* e1_w   = (const float*)d_in[2];
  const float* e1_b   = (const float*)d_in[3];
  const float* bn1_g  = (const float*)d_in[4];
  const float* bn1_b  = (const float*)d_in[5];
  const float* e2_w   = (const float*)d_in[6];
  const float* e2_b   = (const float*)d_in[7];
  const float* bn2_g  = (const float*)d_in[8];
  const float* bn2_b  = (const float*)d_in[9];
  const float* preq_w = (const float*)d_in[10];
  const float* preq_b = (const float*)d_in[11];
  const float* postq_w= (const float*)d_in[12];
  const float* postq_b= (const float*)d_in[13];
  const float* d1_w   = (const float*)d_in[14];
  const float* d1_b   = (const float*)d_in[15];
  const float* bn3_g  = (const float*)d_in[16];
  const float* bn3_b  = (const float*)d_in[17];
  const float* d2_w   = (const float*)d_in[18];
  const float* d2_b   = (const float*)d_in[19];
  const float* bn4_g  = (const float*)d_in[20];
  const float* bn4_b  = (const float*)d_in[21];
  const float* d3_w   = (const float*)d_in[22];
  const float* d3_b   = (const float*)d_in[23];
  float* out = (float*)d_out;
  char* ws = (char*)d_ws;

  double* losspart = (double*)ws;                        // 2048 B
  int*    flagcnt  = (int*)(ws + 2048);
  float*  ss       = (float*)(ws + 4096);
  double* cb64     = (double*)(ws + 8192);               // 512 KB
  double* cbn64    = (double*)(ws + 532480);             // 8 KB
  float*  cbn32    = (float*)(ws + 540672);              // 4 KB
  unsigned short* cbh = (unsigned short*)(ws + 544768);  // 128 KB
  unsigned short* cbl = (unsigned short*)(ws + 675840);  // 128 KB
  int*    flaglist = (int*)(ws + 806912);                // 256 KB
  int*    idx      = (int*)(ws + 1069056);               // 256 KB
  double* part_e1  = (double*)(ws + 1331200);            // 128 KB
  double* part_e2  = (double*)(ws + 1462272);            // 16 KB
  float*  Ptab     = (float*)(ws + 1478656);             // 147 KB (aliases part_d1; dead before d1 writes)
  double* part_d1  = (double*)(ws + 1478656);            // 64 KB
  float*  A        = (float*)(ws + 2097152);             // 16.78 MB
  float*  B        = (float*)(ws + 18874368);            // 1 MB
  float*  Zq       = (float*)(ws + 19922944);            // 16.78 MB
  double* part_d2  = (double*)(ws + 19922944);           // 512 KB, aliases Zq (dead after postq_gather)
  __half* F        = (__half*)(ws + 36700160);           // 67.1 MB (fp16)
  float*  stepb    = (float*)(ws + 36700160);            // 2 MB, aliases F head (dead before d2 writes F)

  float *ss1 = ss + 0, *ss2 = ss + 32, *ss3 = ss + 48, *ss4 = ss + 80;
  float* D = B;   // B dead after preq

  prep_all<<<40, 256, 0, stream>>>(cb, cb64, cbn64, cbn32, cbh, cbl, flagcnt, postq_w, Ptab);

  // encoder
  e1_conv<<<1024, 256, 0, stream>>>(x, e1_w, e1_b, A, part_e1);
  bn_red_fin<<<16, 256, 0, stream>>>(part_e1, 512, bn1_g, bn1_b, ss1, 16, 262144.0);
  e2_conv<<<256, 256, 0, stream>>>(A, e2_w, e2_b, ss1, B, part_e2);
  bn_red_fin<<<4, 256, 0, stream>>>(part_e2, 256, bn2_g, bn2_b, ss2, 4, 65536.0);
  preq_conv<<<4096, 256, 0, stream>>>(B, preq_w, preq_b, ss2, Zq);

  // VQ
  vq_screen_mfma<<<512, 256, 0, stream>>>(Zq, cbh, cbl, cbn32, idx, flagcnt, flaglist, stepb);
  vq_refine<<<128, 256, 0, stream>>>(Zq, cb64, cbn64, flagcnt, flaglist, stepb, idx);

  // decoder (postq_gather also computes VQ loss partials; Zq dead after this)
  postq_gather<<<1024, 256, 0, stream>>>(Ptab, idx, postq_b, D, Zq, cb, losspart);
  convT_cob8<4, 16, 64, 64, false, false><<<512, 256, 0, stream>>>(D, d1_w, d1_b, nullptr, A, part_d1);
  bn_red_fin<<<16, 256, 0, stream>>>(part_d1, 256, bn3_g, bn3_b, ss3, 16, 262144.0);
  convT_cob8<16, 32, 128, 128, true, true><<<4096, 256, 0, stream>>>(A, d2_w, d2_b, ss3, (float*)F, part_d2);
  bn_red_fin<<<32, 256, 0, stream>>>(part_d2, 1024, bn4_g, bn4_b, ss4, 32, 1048576.0);
  d3_tile<<<1024, 256, 0, stream>>>(F, d3_w, d3_b, ss4, out, losspart);
}

// Round 11
// 285.306 us; speedup vs baseline: 1.0197x; 1.0197x over previous
//
#include <hip/hip_runtime.h>
#include <math.h>

#define EPSV 1e-5
#define SLOPE 0.1f

typedef __attribute__((ext_vector_type(4))) float f32x4;
typedef __attribute__((ext_vector_type(8))) short short8x;

__device__ __forceinline__ float lrelu(float x){ return x >= 0.f ? x : SLOPE * x; }
__device__ __forceinline__ float tanh_fast(float x){
  float e = __expf(2.f * x);
  return 1.f - 2.f / (e + 1.f);
}
__device__ __forceinline__ unsigned bf16rne(float f){
  unsigned u = __float_as_uint(f);
  u += 0x7fff + ((u >> 16) & 1);
  return u >> 16;
}

// ---- block BN-stats epilogue: per-thread CL channel sums/sqs -> f64 partials (padded stride) ----
template<int CL>
__device__ __forceinline__ void stats_epilogue(const float* sums, const float* sqs,
    double* __restrict__ part, int chbase, int P, int p, float* sred){
  const int C2 = 2 * CL;
  const int ST = C2 + 1;
  int t = threadIdx.x;
  #pragma unroll
  for (int c = 0; c < CL; c++){
    sred[t * ST + c] = sums[c];
    sred[t * ST + CL + c] = sqs[c];
  }
  __syncthreads();
  if (t < 64){
    int c = t % C2;
    int g = t / C2;
    const int G = 64 / C2;
    const int R = 256 / G;
    double s = 0;
    for (int r = g * R; r < (g + 1) * R; r++) s += (double)sred[r * ST + c];
    #pragma unroll
    for (int off = C2; off < 64; off <<= 1) s += __shfl_xor(s, off);
    if (t < C2){
      int ch = chbase + (c < CL ? c : c - CL);
      part[(size_t)ch * 2 * P + (c < CL ? 0 : P) + p] = s;
    }
  }
}

// ---- reduce partials + finalize scale/shift ----
__global__ __launch_bounds__(256) void bn_red_fin(const double* __restrict__ part, int P,
    const float* __restrict__ g, const float* __restrict__ b, float* __restrict__ ss, int C, double count){
  int c = blockIdx.x;
  __shared__ double r0[256], r1[256];
  int t = threadIdx.x;
  double s = 0, q = 0;
  for (int p = t; p < P; p += 256){
    s += part[(size_t)c * 2 * P + p];
    q += part[(size_t)c * 2 * P + P + p];
  }
  r0[t] = s; r1[t] = q; __syncthreads();
  for (int o = 128; o > 0; o >>= 1){
    if (t < o){ r0[t] += r0[t + o]; r1[t] += r1[t + o]; }
    __syncthreads();
  }
  if (t == 0){
    double m = r0[0] / count;
    double var = r1[0] / count - m * m;
    double scale = (double)g[c] / sqrt(var + EPSV);
    ss[c] = (float)scale;
    ss[C + c] = (float)((double)b[c] - m * scale);
  }
}

// ---------------- e1: 3->16 s2, co-split x2 (8 co/thread), 2 x-outputs, fused bn1-stats ----------------
__global__ __launch_bounds__(256) void e1_conv(const float* __restrict__ x, const float* __restrict__ w,
    const float* __restrict__ bias, float* __restrict__ out, double* __restrict__ part){
  int idx = blockIdx.x * 256 + threadIdx.x;
  int ox2 = idx & 63, oy = (idx >> 6) & 127;
  int cog = (idx >> 13) & 1, n = idx >> 14;
  cog = __builtin_amdgcn_readfirstlane(cog);
  n   = __builtin_amdgcn_readfirstlane(n);
  float acc[8][2];
  #pragma unroll
  for (int co = 0; co < 8; co++){ float b = bias[cog * 8 + co]; acc[co][0] = b; acc[co][1] = b; }
  int ix0 = 4 * ox2 - 1;
  int lclamp = (ox2 > 0) ? ix0 : 0;
  const float* xp = x + (size_t)n * 3 * 65536;
  #pragma unroll
  for (int ci = 0; ci < 3; ci++){
    const float* pl = xp + ci * 65536;
    #pragma unroll
    for (int ky = 0; ky < 3; ky++){
      int iy = 2 * oy - 1 + ky;
      if (iy >= 0){
        const float* row = pl + iy * 256;
        float l = row[lclamp];
        float4 m = *(const float4*)(row + ix0 + 1);
        float v0 = (ox2 > 0) ? l : 0.f;
        #pragma unroll
        for (int co = 0; co < 8; co++){
          const float* wp = w + (((cog * 8 + co) * 3 + ci) * 3 + ky) * 3;
          acc[co][0] = fmaf(v0,  wp[0], acc[co][0]);
          acc[co][0] = fmaf(m.x, wp[1], acc[co][0]);
          acc[co][0] = fmaf(m.y, wp[2], acc[co][0]);
          acc[co][1] = fmaf(m.y, wp[0], acc[co][1]);
          acc[co][1] = fmaf(m.z, wp[1], acc[co][1]);
          acc[co][1] = fmaf(m.w, wp[2], acc[co][1]);
        }
      }
    }
  }
  float sums[8], sqs[8];
  #pragma unroll
  for (int co = 0; co < 8; co++){
    float2 st; st.x = acc[co][0]; st.y = acc[co][1];
    *(float2*)(out + ((size_t)(n * 16 + cog * 8 + co) * 128 + oy) * 128 + 2 * ox2) = st;
    sums[co] = acc[co][0] + acc[co][1];
    sqs[co] = acc[co][0] * acc[co][0] + acc[co][1] * acc[co][1];
  }
  __shared__ float sred[256 * 17];
  int p = ((blockIdx.x >> 6) << 5) + (blockIdx.x & 31);
  stats_epilogue<8>(sums, sqs, part, cog * 8, 512, p, sred);
}

// ---------------- e2: 16->4 s2, co-split x4 (1 co/thread), fused bn1-apply + bn2-stats ----------------
__global__ __launch_bounds__(256) void e2_conv(const float* __restrict__ in, const float* __restrict__ w,
    const float* __restrict__ bias, const float* __restrict__ ssIn, float* __restrict__ out,
    double* __restrict__ part){
  int gid = blockIdx.x * 256 + threadIdx.x;     // 1M = 4co x 65536
  int sp = gid & 65535;
  int co = gid >> 16;
  co = __builtin_amdgcn_readfirstlane(co);
  int ox = sp & 63, oy = (sp >> 6) & 63, n = sp >> 12;
  float acc = bias[co];
  int iy0 = oy * 2 - 1, ix0 = ox * 2 - 1;
  const float* ip = in + (size_t)n * 16 * 16384;
  const float* wb = w + co * 144;
  #pragma unroll
  for (int ky = 0; ky < 3; ky++){
    int iy = iy0 + ky; if ((unsigned)iy >= 128u) continue;
    #pragma unroll
    for (int kx = 0; kx < 3; kx++){
      int ix = ix0 + kx; if ((unsigned)ix >= 128u) continue;
      const float* r = ip + iy * 128 + ix;
      #pragma unroll
      for (int ci = 0; ci < 16; ci++){
        float v = lrelu(fmaf(r[ci * 16384], ssIn[ci], ssIn[16 + ci]));
        acc = fmaf(v, wb[ci * 9 + ky * 3 + kx], acc);
      }
    }
  }
  out[(((size_t)n * 4 + co) * 64 + oy) * 64 + ox] = acc;
  // per-block stats (block-uniform channel co), f64 reduce
  __shared__ double s0[256], s1[256];
  int t = threadIdx.x;
  s0[t] = (double)acc;
  s1[t] = (double)acc * (double)acc;
  __syncthreads();
  for (int o = 128; o > 0; o >>= 1){
    if (t < o){ s0[t] += s0[t + o]; s1[t] += s1[t + o]; }
    __syncthreads();
  }
  if (t == 0){
    int p = blockIdx.x & 255;
    part[(size_t)co * 512 + p] = s0[0];
    part[(size_t)co * 512 + 256 + p] = s1[0];
  }
}

// ---------------- preq: fused bn2-apply, output plane layout Zq[coq][pos][4] ----------------
__global__ __launch_bounds__(256) void preq_conv(const float* __restrict__ in, const float* __restrict__ w,
    const float* __restrict__ bias, const float* __restrict__ ssIn, float* __restrict__ Zq){
  int idx = blockIdx.x * 256 + threadIdx.x;
  int sp = idx & 65535;
  int coq = idx >> 16;
  int x = sp & 63, y = (sp >> 6) & 63, n = sp >> 12;
  float scv[4] = {ssIn[0], ssIn[1], ssIn[2], ssIn[3]};
  float shv[4] = {ssIn[4], ssIn[5], ssIn[6], ssIn[7]};
  float a0 = bias[coq * 4 + 0], a1 = bias[coq * 4 + 1], a2 = bias[coq * 4 + 2], a3 = bias[coq * 4 + 3];
  const float* ip = in + (size_t)n * 4 * 4096;
  #pragma unroll
  for (int ky = 0; ky < 3; ky++){
    int iy = y - 1 + ky; if ((unsigned)iy >= 64u) continue;
    #pragma unroll
    for (int kx = 0; kx < 3; kx++){
      int ix = x - 1 + kx; if ((unsigned)ix >= 64u) continue;
      #pragma unroll
      for (int ci = 0; ci < 4; ci++){
        float v = lrelu(fmaf(ip[ci * 4096 + iy * 64 + ix], scv[ci], shv[ci]));
        const float* wp = w + ((coq * 4) * 4 + ci) * 9 + ky * 3 + kx;
        a0 = fmaf(v, wp[0], a0);
        a1 = fmaf(v, wp[36], a1);
        a2 = fmaf(v, wp[72], a2);
        a3 = fmaf(v, wp[108], a3);
      }
    }
  }
  float4 o; o.x = a0; o.y = a1; o.z = a2; o.w = a3;
  ((float4*)Zq)[coq * 65536 + sp] = o;
}

// ---------------- prep_all: blocks 0-3 VQ codebook prep, blocks 4-39 postq P-table ----------------
__global__ __launch_bounds__(256) void prep_all(const float* __restrict__ cb, double* __restrict__ cb64,
    double* __restrict__ cbn64, float* __restrict__ cbn32, unsigned short* __restrict__ cbh,
    unsigned short* __restrict__ cbl, int* __restrict__ flagcnt,
    const float* __restrict__ pw, float* __restrict__ P){
  int t = threadIdx.x;
  if (blockIdx.x < 4){
    int k = blockIdx.x * 256 + t;
    if (k == 0) flagcnt[0] = 0;
    double s = 0;
    for (int d = 0; d < 64; d++){
      float v = cb[k * 64 + d];
      cb64[(size_t)k * 64 + d] = (double)v;
      s = fma((double)v, (double)v, s);
      unsigned h = bf16rne(v);
      float hf = __uint_as_float(h << 16);
      unsigned l = bf16rne(v - hf);
      cbh[k * 64 + d] = (unsigned short)h;
      cbl[k * 64 + d] = (unsigned short)l;
    }
    cbn64[k] = s;
    cbn32[k] = (float)s;
  } else {
    int gid = (blockIdx.x - 4) * 256 + t;
    if (gid >= 9216) return;
    int k = gid / 9, tap = gid - k * 9;
    float a0 = 0.f, a1 = 0.f, a2 = 0.f, a3 = 0.f;
    const float* cp = cb + (k << 6);
    #pragma unroll 16
    for (int ci = 0; ci < 64; ci++){
      float c = cp[ci];
      a0 = fmaf(c, pw[(0 * 64 + ci) * 9 + tap], a0);
      a1 = fmaf(c, pw[(1 * 64 + ci) * 9 + tap], a1);
      a2 = fmaf(c, pw[(2 * 64 + ci) * 9 + tap], a2);
      a3 = fmaf(c, pw[(3 * 64 + ci) * 9 + tap], a3);
    }
    float4 o; o.x = a0; o.y = a1; o.z = a2; o.w = a3;
    ((float4*)P)[gid] = o;
  }
}

// ---------------- VQ screen via MFMA: per-step (128-code) partial bests + global merge ----------------
__global__ __launch_bounds__(256) void vq_screen_mfma(const float* __restrict__ Zq,
    const unsigned short* __restrict__ cbh, const unsigned short* __restrict__ cbl,
    const float* __restrict__ cbn32, int* __restrict__ idxout,
    int* __restrict__ flagcnt, int* __restrict__ flaglist, float* __restrict__ stepb){
  __shared__ unsigned short lcb[32 * 64 * 8];
  __shared__ float lcn[128];
  int t = threadIdx.x;
  int lane = t & 63;
  int w = t >> 6;
  int col = lane & 15, hg = lane >> 4;
  int pos0 = blockIdx.x * 128 + w * 32;
  int posA = pos0 + col, posB = pos0 + 16 + col;
  const float4* Zq4 = (const float4*)Zq;
  short8x zhA[2], zlA[2], zhB[2], zlB[2];
  #pragma unroll
  for (int kc = 0; kc < 2; kc++){
    #pragma unroll
    for (int tb = 0; tb < 2; tb++){
      int pos = tb ? posB : posA;
      float4 f0 = Zq4[(size_t)(8 * kc + 2 * hg) * 65536 + pos];
      float4 f1 = Zq4[(size_t)(8 * kc + 2 * hg + 1) * 65536 + pos];
      float zv[8] = {f0.x, f0.y, f0.z, f0.w, f1.x, f1.y, f1.z, f1.w};
      union { unsigned u[4]; short8x v; } H, L;
      #pragma unroll
      for (int j = 0; j < 4; j++){
        unsigned h0 = bf16rne(zv[2 * j]);
        unsigned h1 = bf16rne(zv[2 * j + 1]);
        float hf0 = __uint_as_float(h0 << 16);
        float hf1 = __uint_as_float(h1 << 16);
        unsigned l0 = bf16rne(zv[2 * j] - hf0);
        unsigned l1 = bf16rne(zv[2 * j + 1] - hf1);
        H.u[j] = h0 | (h1 << 16);
        L.u[j] = l0 | (l1 << 16);
      }
      if (tb){ zhB[kc] = H.v; zlB[kc] = L.v; } else { zhA[kc] = H.v; zlA[kc] = L.v; }
    }
  }
  float BA = 3.0e38f, SA = 3.0e38f, BB = 3.0e38f, SBt = 3.0e38f;
  int IA = 0, IB = 0;
  for (int step = 0; step < 8; step++){
    int code0 = step * 128;
    __syncthreads();
    #pragma unroll
    for (int i = 0; i < 8; i++){
      int piece = i * 256 + t;
      int fb = piece >> 6, pl = piece & 63;
      int g = fb >> 2, kc = (fb >> 1) & 1, sp = fb & 1;
      const unsigned short* src = (sp ? cbl : cbh)
          + ((size_t)(code0 + g * 16 + (pl & 15)) << 6) + kc * 32 + ((pl >> 4) << 3);
      *(uint4*)&lcb[piece * 8] = *(const uint4*)src;
    }
    if (t < 128) lcn[t] = cbn32[code0 + t];
    __syncthreads();
    float bA = 3.0e38f, sA = 3.0e38f, bB = 3.0e38f, sB = 3.0e38f;
    int iA = 0, iB = 0;
    #pragma unroll 2
    for (int g = 0; g < 8; g++){
      const short8x* lc8 = (const short8x*)lcb;
      short8x Ah0 = lc8[(g * 4 + 0) * 64 + lane];
      short8x Al0 = lc8[(g * 4 + 1) * 64 + lane];
      short8x Ah1 = lc8[(g * 4 + 2) * 64 + lane];
      short8x Al1 = lc8[(g * 4 + 3) * 64 + lane];
      f32x4 accA = {0.f, 0.f, 0.f, 0.f};
      f32x4 accB = {0.f, 0.f, 0.f, 0.f};
      accA = __builtin_amdgcn_mfma_f32_16x16x32_bf16(Ah0, zhA[0], accA, 0, 0, 0);
      accA = __builtin_amdgcn_mfma_f32_16x16x32_bf16(Ah1, zhA[1], accA, 0, 0, 0);
      accA = __builtin_amdgcn_mfma_f32_16x16x32_bf16(Ah0, zlA[0], accA, 0, 0, 0);
      accA = __builtin_amdgcn_mfma_f32_16x16x32_bf16(Ah1, zlA[1], accA, 0, 0, 0);
      accA = __builtin_amdgcn_mfma_f32_16x16x32_bf16(Al0, zhA[0], accA, 0, 0, 0);
      accA = __builtin_amdgcn_mfma_f32_16x16x32_bf16(Al1, zhA[1], accA, 0, 0, 0);
      accB = __builtin_amdgcn_mfma_f32_16x16x32_bf16(Ah0, zhB[0], accB, 0, 0, 0);
      accB = __builtin_amdgcn_mfma_f32_16x16x32_bf16(Ah1, zhB[1], accB, 0, 0, 0);
      accB = __builtin_amdgcn_mfma_f32_16x16x32_bf16(Ah0, zlB[0], accB, 0, 0, 0);
      accB = __builtin_amdgcn_mfma_f32_16x16x32_bf16(Ah1, zlB[1], accB, 0, 0, 0);
      accB = __builtin_amdgcn_mfma_f32_16x16x32_bf16(Al0, zhB[0], accB, 0, 0, 0);
      accB = __builtin_amdgcn_mfma_f32_16x16x32_bf16(Al1, zhB[1], accB, 0, 0, 0);
      int cbase = code0 + g * 16 + 4 * hg;
      #pragma unroll
      for (int r = 0; r < 4; r++){
        float cn = lcn[g * 16 + 4 * hg + r];
        float vA = fmaf(accA[r], -2.0f, cn);
        sA = fminf(sA, fmaxf(vA, bA));
        if (vA < bA){ bA = vA; iA = cbase + r; }
        float vB = fmaf(accB[r], -2.0f, cn);
        sB = fminf(sB, fmaxf(vB, bB));
        if (vB < bB){ bB = vB; iB = cbase + r; }
      }
    }
    #pragma unroll
    for (int off = 16; off <= 32; off <<= 1){
      float ob = __shfl_xor(bA, off);
      float os = __shfl_xor(sA, off);
      int oi = __shfl_xor(iA, off);
      sA = fminf(fminf(sA, os), fmaxf(bA, ob));
      if (ob < bA){ bA = ob; iA = oi; }
      ob = __shfl_xor(bB, off);
      os = __shfl_xor(sB, off);
      oi = __shfl_xor(iB, off);
      sB = fminf(fminf(sB, os), fmaxf(bB, ob));
      if (ob < bB){ bB = ob; iB = oi; }
    }
    if (hg == 0){
      stepb[step * 65536 + posA] = bA;
      stepb[step * 65536 + posB] = bB;
    }
    if (bA < BA){ SA = fminf(BA, sA); BA = bA; IA = iA; } else SA = fminf(SA, bA);
    if (bB < BB){ SBt = fminf(BB, sB); BB = bB; IB = iB; } else SBt = fminf(SBt, bB);
  }
  if (hg == 0){
    idxout[posA] = IA;
    if (SA - BA < 1.2e-2f){
      int slot = atomicAdd(flagcnt, 1);
      flaglist[slot] = posA;
    }
    idxout[posB] = IB;
    if (SBt - BB < 1.2e-2f){
      int slot = atomicAdd(flagcnt, 1);
      flaglist[slot] = posB;
    }
  }
}

// ---------------- VQ refine: exact f64 re-rank over candidate steps only ----------------
__global__ __launch_bounds__(256) void vq_refine(const float* __restrict__ Zq, const double* __restrict__ cb64,
    const double* __restrict__ cbn64, const int* __restrict__ flagcnt, const int* __restrict__ flaglist,
    const float* __restrict__ stepb, int* __restrict__ idxout){
  int gw = (blockIdx.x * 256 + threadIdx.x) >> 6;
  int lane = threadIdx.x & 63;
  int nf = flagcnt[0];
  for (int f = gw; f < nf; f += 512){
    int pos = flaglist[f];
    float zr[64];
    #pragma unroll
    for (int q = 0; q < 16; q++){
      float4 v = ((const float4*)Zq)[q * 65536 + pos];
      zr[4 * q] = v.x; zr[4 * q + 1] = v.y; zr[4 * q + 2] = v.z; zr[4 * q + 3] = v.w;
    }
    float sb[8];
    float B = 3.0e38f;
    #pragma unroll
    for (int s = 0; s < 8; s++){ sb[s] = stepb[s * 65536 + pos]; B = fminf(B, sb[s]); }
    float lim = B + 1.2e-2f;
    double best = 1e300; int bi = 1 << 30;
    #pragma unroll
    for (int s = 0; s < 8; s++){
      if (sb[s] < lim){
        int k0 = s * 128 + 2 * lane;
        #pragma unroll
        for (int kk = 0; kk < 2; kk++){
          int k = k0 + kk;
          const double* c = cb64 + (size_t)k * 64;
          double a0 = 0, a1 = 0, a2 = 0, a3 = 0;
          #pragma unroll
          for (int d = 0; d < 64; d += 4){
            a0 = fma(c[d], (double)zr[d], a0);
            a1 = fma(c[d + 1], (double)zr[d + 1], a1);
            a2 = fma(c[d + 2], (double)zr[d + 2], a2);
            a3 = fma(c[d + 3], (double)zr[d + 3], a3);
          }
          double sc = cbn64[k] - 2.0 * ((a0 + a1) + (a2 + a3));
          if (sc < best){ best = sc; bi = k; }
        }
      }
    }
    #pragma unroll
    for (int o = 32; o > 0; o >>= 1){
      double ob = __shfl_xor(best, o);
      int oi = __shfl_xor(bi, o);
      if (ob < best || (ob == best && oi < bi)){ best = ob; bi = oi; }
    }
    if (lane == 0) idxout[pos] = bi;
  }
}

// ---------------- postq gather: out[pos][co] = bias + sum_tap P[idx[nbr]][tap][co]; fused loss ----------------
__global__ __launch_bounds__(256) void postq_gather(const float* __restrict__ P, const int* __restrict__ idxm,
    const float* __restrict__ bias, float* __restrict__ out,
    const float* __restrict__ Zq, const float* __restrict__ cb, double* __restrict__ losspart){
  int gid = blockIdx.x * 256 + threadIdx.x;
  int sp = gid & 65535;
  int co = gid >> 16;
  co = __builtin_amdgcn_readfirstlane(co);
  int xx = sp & 63, yy = (sp >> 6) & 63, n = sp >> 12;
  float acc = bias[co];
  #pragma unroll
  for (int ky = 0; ky < 3; ky++){
    int iy = yy - 1 + ky; if ((unsigned)iy >= 64u) continue;
    #pragma unroll
    for (int kx = 0; kx < 3; kx++){
      int ix = xx - 1 + kx; if ((unsigned)ix >= 64u) continue;
      int spt = (n << 12) + (iy << 6) + ix;
      int k = idxm[spt];
      acc += P[(k * 9 + (ky * 3 + kx)) * 4 + co];
    }
  }
  out[((size_t)(n * 4 + co) << 12) + (yy << 6) + xx] = acc;
  if (co == 0){
    int k = idxm[sp];
    const float4* c4 = (const float4*)(cb + (k << 6));
    double l = 0;
    #pragma unroll
    for (int q = 0; q < 16; q++){
      float4 z = ((const float4*)Zq)[q * 65536 + sp];
      float4 c = c4[q];
      float d0 = z.x - c.x, d1 = z.y - c.y, d2 = z.z - c.z, d3 = z.w - c.w;
      l += (double)d0 * d0 + (double)d1 * d1 + (double)d2 * d2 + (double)d3 * d3;
    }
    __shared__ double sb[256];
    int t = threadIdx.x;
    sb[t] = l; __syncthreads();
    for (int o = 128; o > 0; o >>= 1){
      if (t < o) sb[t] += sb[t + o];
      __syncthreads();
    }
    if (t == 0) losspart[blockIdx.x] = sb[0];
  }
}

// ---------------- transposed conv k3 s2 p1 op1, 8 co/thread, optional input-BN, fused stats ----------------
template<int CI, int CO, int IHt, int IWt, bool APPLY>
__global__ __launch_bounds__(256) void convT_cob8(const float* __restrict__ in, const float* __restrict__ w,
    const float* __restrict__ bias, const float* __restrict__ ssIn, float* __restrict__ out,
    double* __restrict__ part){
  constexpr int SB = IHt * IWt / 256;
  constexpr int COG = CO / 8;
  constexpr int P = 16 * SB;
  const int OW = IWt * 2;
  int idx = blockIdx.x * 256 + threadIdx.x;
  int ix = idx % IWt, iy = (idx / IWt) % IHt;
  int cog = (idx / (IWt * IHt)) % COG, n = idx / (IWt * IHt * COG);
  cog = __builtin_amdgcn_readfirstlane(cog);
  n   = __builtin_amdgcn_readfirstlane(n);
  float a00[8], a01[8], a10[8], a11[8];
  #pragma unroll
  for (int j = 0; j < 8; j++){ float b = bias[cog * 8 + j]; a00[j] = b; a01[j] = b; a10[j] = b; a11[j] = b; }
  bool okx = (ix + 1 < IWt), oky = (iy + 1 < IHt);
  int ixp = okx ? ix + 1 : ix, iyp = oky ? iy + 1 : iy;
  const float* ip = in + (size_t)n * CI * IHt * IWt;
  #pragma unroll 4
  for (int ci = 0; ci < CI; ci++){
    const float* p = ip + ci * IHt * IWt;
    float v00 = p[iy * IWt + ix];
    float v01 = p[iy * IWt + ixp];
    float v10 = p[iyp * IWt + ix];
    float v11 = p[iyp * IWt + ixp];
    if (APPLY){
      float sc = ssIn[ci], sh = ssIn[CI + ci];
      v00 = lrelu(fmaf(v00, sc, sh));
      v01 = lrelu(fmaf(v01, sc, sh));
      v10 = lrelu(fmaf(v10, sc, sh));
      v11 = lrelu(fmaf(v11, sc, sh));
    }
    if (!okx) v01 = 0.f;
    if (!oky) v10 = 0.f;
    if (!(okx && oky)) v11 = 0.f;
    const float* wp = w + ((size_t)ci * CO + cog * 8) * 9;
    #pragma unroll
    for (int j = 0; j < 8; j++){
      const float* q = wp + j * 9;
      a00[j] = fmaf(q[4], v00, a00[j]);
      a01[j] = fmaf(q[3], v01, a01[j]); a01[j] = fmaf(q[5], v00, a01[j]);
      a10[j] = fmaf(q[1], v10, a10[j]); a10[j] = fmaf(q[7], v00, a10[j]);
      a11[j] = fmaf(q[0], v11, a11[j]); a11[j] = fmaf(q[2], v10, a11[j]);
      a11[j] = fmaf(q[6], v01, a11[j]); a11[j] = fmaf(q[8], v00, a11[j]);
    }
  }
  float sums[8], sqs[8];
  #pragma unroll
  for (int j = 0; j < 8; j++){
    float* o = out + (((size_t)n * CO + cog * 8 + j) * (IHt * 2) + 2 * iy) * OW + 2 * ix;
    float2 r0; r0.x = a00[j]; r0.y = a01[j];
    float2 r1; r1.x = a10[j]; r1.y = a11[j];
    *(float2*)o = r0;
    *(float2*)(o + OW) = r1;
    sums[j] = (a00[j] + a01[j]) + (a10[j] + a11[j]);
    sqs[j] = (a00[j] * a00[j] + a01[j] * a01[j]) + (a10[j] * a10[j] + a11[j] * a11[j]);
  }
  __shared__ float sred[256 * 17];
  int sb = blockIdx.x % SB;
  stats_epilogue<8>(sums, sqs, part, cog * 8, P, n * SB + sb, sred);
}

// ---------------- d3: 32->3 @256x256, LDS-tiled 128px x 4row (12.75 KB), fused bn4 + loss ----------------
// 128 threads: 32 xl x 4 r; grid 2048 = 16n x 64 oyb x 2 xh; ci chunks of 4
__global__ __launch_bounds__(128) void d3_tile(const float* __restrict__ F, const float* __restrict__ w,
    const float* __restrict__ bias, const float* __restrict__ ss, float* __restrict__ out,
    const double* __restrict__ losspart){
  __shared__ float st[4 * 6 * 136];             // 13056 B
  int t = threadIdx.x;
  int xl = t & 31, r = t >> 5;
  int n = blockIdx.x >> 7, oyb = (blockIdx.x >> 1) & 63, xh = blockIdx.x & 1;
  int oy = oyb * 4 + r;
  if (blockIdx.x == 0 && t < 64){
    double s = losspart[t] + losspart[t + 64] + losspart[t + 128] + losspart[t + 192];
    #pragma unroll
    for (int o = 32; o > 0; o >>= 1) s += __shfl_xor(s, o);
    if (t == 0) out[3145728] = (float)(1.25 * s / (65536.0 * 64.0));
  }
  float acc[3][4];
  #pragma unroll
  for (int co = 0; co < 3; co++){
    float b = bias[co];
    #pragma unroll
    for (int j = 0; j < 4; j++) acc[co][j] = b;
  }
  const float* base = F + (size_t)n * 32 * 65536;
  int gx0 = xh * 128 - 4;
  for (int cc = 0; cc < 8; cc++){
    int cib = cc * 4;
    // stage 4 ci x 6 rows x 136 px (34 float4 each) = 816 pieces
    #pragma unroll
    for (int j = 0; j < 7; j++){
      int p = j * 128 + t;
      if (p < 816){
        int xq = p % 34;
        int rem = p / 34;
        int rr = rem % 6, cl = rem / 6;
        int g = oyb * 4 - 1 + rr;
        int gx = gx0 + 4 * xq;
        float4 v;
        if ((unsigned)g < 256u && (unsigned)gx <= 252u){
          v = *(const float4*)(base + ((size_t)(cib + cl) * 256 + g) * 256 + gx);
          float sc = ss[cib + cl], sh = ss[32 + cib + cl];
          v.x = lrelu(fmaf(v.x, sc, sh));
          v.y = lrelu(fmaf(v.y, sc, sh));
          v.z = lrelu(fmaf(v.z, sc, sh));
          v.w = lrelu(fmaf(v.w, sc, sh));
        } else {
          v.x = 0.f; v.y = 0.f; v.z = 0.f; v.w = 0.f;
        }
        *(float4*)&st[(cl * 6 + rr) * 136 + 4 * xq] = v;
      }
    }
    __syncthreads();
    #pragma unroll
    for (int cl = 0; cl < 4; cl++){
      #pragma unroll
      for (int ky = 0; ky < 3; ky++){
        int rowb = (cl * 6 + r + ky) * 136;
        float4 A = *(const float4*)&st[rowb + 4 + 4 * xl];
        float u0 = st[rowb + 3 + 4 * xl];
        float u5 = st[rowb + 8 + 4 * xl];
        float u[6] = {u0, A.x, A.y, A.z, A.w, u5};
        #pragma unroll
        for (int co = 0; co < 3; co++){
          const float* wp = w + ((co * 32 + cib + cl) * 9) + ky * 3;
          #pragma unroll
          for (int j = 0; j < 4; j++){
            acc[co][j] = fmaf(u[j],     wp[0], acc[co][j]);
            acc[co][j] = fmaf(u[j + 1], wp[1], acc[co][j]);
            acc[co][j] = fmaf(u[j + 2], wp[2], acc[co][j]);
          }
        }
      }
    }
    __syncthreads();
  }
  #pragma unroll
  for (int co = 0; co < 3; co++){
    float4 s0;
    s0.x = tanh_fast(acc[co][0]); s0.y = tanh_fast(acc[co][1]);
    s0.z = tanh_fast(acc[co][2]); s0.w = tanh_fast(acc[co][3]);
    float* o = out + ((size_t)(n * 3 + co) * 256 + oy) * 256 + xh * 128 + 4 * xl;
    *(float4*)o = s0;
  }
}

// ---------------- launch ----------------
extern "C" void kernel_launch(void* const* d_in, const int* in_sizes, int n_in,
                              void* d_out, int out_size, void* d_ws, size_t ws_size,
                              hipStream_t stream){
  const float* x      = (const float*)d_in[0];
  const float* cb     = (const float*)d_in[1];
  const float* e1_w   = (const float*)d_in[2];
  const float* e1_b   = (const float*)d_in[3];
  const float* bn1_g  = (const float*)d_in[4];
  const float* bn1_b  = (const float*)d_in[5];
  const float* e2_w   = (const float*)d_in[6];
  const float* e2_b   = (const float*)d_in[7];
  const float* bn2_g  = (const float*)d_in[8];
  const float* bn2_b  = (const float*)d_in[9];
  const float* preq_w = (const float*)d_in[10];
  const float* preq_b = (const float*)d_in[11];
  const float* postq_w= (const float*)d_in[12];
  const float* postq_b= (const float*)d_in[13];
  const float* d1_w   = (const float*)d_in[14];
  const float* d1_b   = (const float*)d_in[15];
  const float* bn3_g  = (const float*)d_in[16];
  const float* bn3_b  = (const float*)d_in[17];
  const float* d2_w   = (const float*)d_in[18];
  const float* d2_b   = (const float*)d_in[19];
  const float* bn4_g  = (const float*)d_in[20];
  const float* bn4_b  = (const float*)d_in[21];
  const float* d3_w   = (const float*)d_in[22];
  const float* d3_b   = (const float*)d_in[23];
  float* out = (float*)d_out;
  char* ws = (char*)d_ws;

  double* losspart = (double*)ws;                        // 2048 B
  int*    flagcnt  = (int*)(ws + 2048);
  float*  ss       = (float*)(ws + 4096);
  double* cb64     = (double*)(ws + 8192);               // 512 KB
  double* cbn64    = (double*)(ws + 532480);             // 8 KB
  float*  cbn32    = (float*)(ws + 540672);              // 4 KB
  unsigned short* cbh = (unsigned short*)(ws + 544768);  // 128 KB
  unsigned short* cbl = (unsigned short*)(ws + 675840);  // 128 KB
  int*    flaglist = (int*)(ws + 806912);                // 256 KB
  int*    idx      = (int*)(ws + 1069056);               // 256 KB
  double* part_e1  = (double*)(ws + 1331200);            // 128 KB
  double* part_e2  = (double*)(ws + 1462272);            // 16 KB
  float*  Ptab     = (float*)(ws + 1478656);             // 147 KB (aliases part_d1; dead before d1 writes)
  double* part_d1  = (double*)(ws + 1478656);            // 64 KB
  float*  A        = (float*)(ws + 2097152);             // 16.78 MB
  float*  B        = (float*)(ws + 18874368);            // 1 MB
  float*  Zq       = (float*)(ws + 19922944);            // 16.78 MB
  double* part_d2  = (double*)(ws + 19922944);           // 512 KB, aliases Zq (dead after postq_gather)
  float*  F        = (float*)(ws + 36700160);            // 134.2 MB
  float*  stepb    = (float*)(ws + 36700160);            // 2 MB, aliases F head (dead before d2 writes F)

  float *ss1 = ss + 0, *ss2 = ss + 32, *ss3 = ss + 48, *ss4 = ss + 80;
  float* D = B;   // B dead after preq

  prep_all<<<40, 256, 0, stream>>>(cb, cb64, cbn64, cbn32, cbh, cbl, flagcnt, postq_w, Ptab);

  // encoder
  e1_conv<<<1024, 256, 0, stream>>>(x, e1_w, e1_b, A, part_e1);
  bn_red_fin<<<16, 256, 0, stream>>>(part_e1, 512, bn1_g, bn1_b, ss1, 16, 262144.0);
  e2_conv<<<1024, 256, 0, stream>>>(A, e2_w, e2_b, ss1, B, part_e2);
  bn_red_fin<<<4, 256, 0, stream>>>(part_e2, 256, bn2_g, bn2_b, ss2, 4, 65536.0);
  preq_conv<<<4096, 256, 0, stream>>>(B, preq_w, preq_b, ss2, Zq);

  // VQ
  vq_screen_mfma<<<512, 256, 0, stream>>>(Zq, cbh, cbl, cbn32, idx, flagcnt, flaglist, stepb);
  vq_refine<<<128, 256, 0, stream>>>(Zq, cb64, cbn64, flagcnt, flaglist, stepb, idx);

  // decoder (postq_gather also computes VQ loss partials; Zq dead after this)
  postq_gather<<<1024, 256, 0, stream>>>(Ptab, idx, postq_b, D, Zq, cb, losspart);
  convT_cob8<4, 16, 64, 64, false><<<512, 256, 0, stream>>>(D, d1_w, d1_b, nullptr, A, part_d1);
  bn_red_fin<<<16, 256, 0, stream>>>(part_d1, 256, bn3_g, bn3_b, ss3, 16, 262144.0);
  convT_cob8<16, 32, 128, 128, true><<<4096, 256, 0, stream>>>(A, d2_w, d2_b, ss3, F, part_d2);
  bn_red_fin<<<32, 256, 0, stream>>>(part_d2, 1024, bn4_g, bn4_b, ss4, 32, 1048576.0);
  d3_tile<<<2048, 128, 0, stream>>>(F, d3_w, d3_b, ss4, out, losspart);
}

// Round 12
// 273.307 us; speedup vs baseline: 1.0645x; 1.0439x over previous
//
#include <hip/hip_runtime.h>
#include <math.h>

#define EPSV 1e-5
#define SLOPE 0.1f

typedef __attribute__((ext_vector_type(4))) float f32x4;
typedef __attribute__((ext_vector_type(8))) short short8x;

__device__ __forceinline__ float lrelu(float x){ return x >= 0.f ? x : SLOPE * x; }
__device__ __forceinline__ float tanh_fast(float x){
  float e = __expf(2.f * x);
  return 1.f - 2.f / (e + 1.f);
}
__device__ __forceinline__ unsigned bf16rne(float f){
  unsigned u = __float_as_uint(f);
  u += 0x7fff + ((u >> 16) & 1);
  return u >> 16;
}

// ---- block BN-stats epilogue: per-thread CL channel sums/sqs -> f64 partials (padded stride) ----
template<int CL>
__device__ __forceinline__ void stats_epilogue(const float* sums, const float* sqs,
    double* __restrict__ part, int chbase, int P, int p, float* sred){
  const int C2 = 2 * CL;
  const int ST = C2 + 1;
  int t = threadIdx.x;
  #pragma unroll
  for (int c = 0; c < CL; c++){
    sred[t * ST + c] = sums[c];
    sred[t * ST + CL + c] = sqs[c];
  }
  __syncthreads();
  if (t < 64){
    int c = t % C2;
    int g = t / C2;
    const int G = 64 / C2;
    const int R = 256 / G;
    double s = 0;
    for (int r = g * R; r < (g + 1) * R; r++) s += (double)sred[r * ST + c];
    #pragma unroll
    for (int off = C2; off < 64; off <<= 1) s += __shfl_xor(s, off);
    if (t < C2){
      int ch = chbase + (c < CL ? c : c - CL);
      part[(size_t)ch * 2 * P + (c < CL ? 0 : P) + p] = s;
    }
  }
}

// ---- reduce partials + finalize scale/shift ----
__global__ __launch_bounds__(256) void bn_red_fin(const double* __restrict__ part, int P,
    const float* __restrict__ g, const float* __restrict__ b, float* __restrict__ ss, int C, double count){
  int c = blockIdx.x;
  __shared__ double r0[256], r1[256];
  int t = threadIdx.x;
  double s = 0, q = 0;
  for (int p = t; p < P; p += 256){
    s += part[(size_t)c * 2 * P + p];
    q += part[(size_t)c * 2 * P + P + p];
  }
  r0[t] = s; r1[t] = q; __syncthreads();
  for (int o = 128; o > 0; o >>= 1){
    if (t < o){ r0[t] += r0[t + o]; r1[t] += r1[t + o]; }
    __syncthreads();
  }
  if (t == 0){
    double m = r0[0] / count;
    double var = r1[0] / count - m * m;
    double scale = (double)g[c] / sqrt(var + EPSV);
    ss[c] = (float)scale;
    ss[C + c] = (float)((double)b[c] - m * scale);
  }
}

// ---------------- e1: 3->16 s2, co-split x2 (8 co/thread), 2 x-outputs, fused bn1-stats ----------------
__global__ __launch_bounds__(256) void e1_conv(const float* __restrict__ x, const float* __restrict__ w,
    const float* __restrict__ bias, float* __restrict__ out, double* __restrict__ part){
  int idx = blockIdx.x * 256 + threadIdx.x;
  int ox2 = idx & 63, oy = (idx >> 6) & 127;
  int cog = (idx >> 13) & 1, n = idx >> 14;
  cog = __builtin_amdgcn_readfirstlane(cog);
  n   = __builtin_amdgcn_readfirstlane(n);
  float acc[8][2];
  #pragma unroll
  for (int co = 0; co < 8; co++){ float b = bias[cog * 8 + co]; acc[co][0] = b; acc[co][1] = b; }
  int ix0 = 4 * ox2 - 1;
  int lclamp = (ox2 > 0) ? ix0 : 0;
  const float* xp = x + (size_t)n * 3 * 65536;
  #pragma unroll
  for (int ci = 0; ci < 3; ci++){
    const float* pl = xp + ci * 65536;
    #pragma unroll
    for (int ky = 0; ky < 3; ky++){
      int iy = 2 * oy - 1 + ky;
      if (iy >= 0){
        const float* row = pl + iy * 256;
        float l = row[lclamp];
        float4 m = *(const float4*)(row + ix0 + 1);
        float v0 = (ox2 > 0) ? l : 0.f;
        #pragma unroll
        for (int co = 0; co < 8; co++){
          const float* wp = w + (((cog * 8 + co) * 3 + ci) * 3 + ky) * 3;
          acc[co][0] = fmaf(v0,  wp[0], acc[co][0]);
          acc[co][0] = fmaf(m.x, wp[1], acc[co][0]);
          acc[co][0] = fmaf(m.y, wp[2], acc[co][0]);
          acc[co][1] = fmaf(m.y, wp[0], acc[co][1]);
          acc[co][1] = fmaf(m.z, wp[1], acc[co][1]);
          acc[co][1] = fmaf(m.w, wp[2], acc[co][1]);
        }
      }
    }
  }
  float sums[8], sqs[8];
  #pragma unroll
  for (int co = 0; co < 8; co++){
    float2 st; st.x = acc[co][0]; st.y = acc[co][1];
    *(float2*)(out + ((size_t)(n * 16 + cog * 8 + co) * 128 + oy) * 128 + 2 * ox2) = st;
    sums[co] = acc[co][0] + acc[co][1];
    sqs[co] = acc[co][0] * acc[co][0] + acc[co][1] * acc[co][1];
  }
  __shared__ float sred[256 * 17];
  int p = ((blockIdx.x >> 6) << 5) + (blockIdx.x & 31);
  stats_epilogue<8>(sums, sqs, part, cog * 8, 512, p, sred);
}

// ---------------- e2: 16->4 s2, co-split x4 (1 co/thread), fused bn1-apply + bn2-stats ----------------
__global__ __launch_bounds__(256) void e2_conv(const float* __restrict__ in, const float* __restrict__ w,
    const float* __restrict__ bias, const float* __restrict__ ssIn, float* __restrict__ out,
    double* __restrict__ part){
  int gid = blockIdx.x * 256 + threadIdx.x;     // 1M = 4co x 65536
  int sp = gid & 65535;
  int co = gid >> 16;
  co = __builtin_amdgcn_readfirstlane(co);
  int ox = sp & 63, oy = (sp >> 6) & 63, n = sp >> 12;
  float acc = bias[co];
  int iy0 = oy * 2 - 1, ix0 = ox * 2 - 1;
  const float* ip = in + (size_t)n * 16 * 16384;
  const float* wb = w + co * 144;
  #pragma unroll
  for (int ky = 0; ky < 3; ky++){
    int iy = iy0 + ky; if ((unsigned)iy >= 128u) continue;
    #pragma unroll
    for (int kx = 0; kx < 3; kx++){
      int ix = ix0 + kx; if ((unsigned)ix >= 128u) continue;
      const float* r = ip + iy * 128 + ix;
      #pragma unroll
      for (int ci = 0; ci < 16; ci++){
        float v = lrelu(fmaf(r[ci * 16384], ssIn[ci], ssIn[16 + ci]));
        acc = fmaf(v, wb[ci * 9 + ky * 3 + kx], acc);
      }
    }
  }
  out[(((size_t)n * 4 + co) * 64 + oy) * 64 + ox] = acc;
  __shared__ double s0[256], s1[256];
  int t = threadIdx.x;
  s0[t] = (double)acc;
  s1[t] = (double)acc * (double)acc;
  __syncthreads();
  for (int o = 128; o > 0; o >>= 1){
    if (t < o){ s0[t] += s0[t + o]; s1[t] += s1[t + o]; }
    __syncthreads();
  }
  if (t == 0){
    int p = blockIdx.x & 255;
    part[(size_t)co * 512 + p] = s0[0];
    part[(size_t)co * 512 + 256 + p] = s1[0];
  }
}

// ---------------- preq: fused bn2-apply, output plane layout Zq[coq][pos][4] ----------------
__global__ __launch_bounds__(256) void preq_conv(const float* __restrict__ in, const float* __restrict__ w,
    const float* __restrict__ bias, const float* __restrict__ ssIn, float* __restrict__ Zq){
  int idx = blockIdx.x * 256 + threadIdx.x;
  int sp = idx & 65535;
  int coq = idx >> 16;
  int x = sp & 63, y = (sp >> 6) & 63, n = sp >> 12;
  float scv[4] = {ssIn[0], ssIn[1], ssIn[2], ssIn[3]};
  float shv[4] = {ssIn[4], ssIn[5], ssIn[6], ssIn[7]};
  float a0 = bias[coq * 4 + 0], a1 = bias[coq * 4 + 1], a2 = bias[coq * 4 + 2], a3 = bias[coq * 4 + 3];
  const float* ip = in + (size_t)n * 4 * 4096;
  #pragma unroll
  for (int ky = 0; ky < 3; ky++){
    int iy = y - 1 + ky; if ((unsigned)iy >= 64u) continue;
    #pragma unroll
    for (int kx = 0; kx < 3; kx++){
      int ix = x - 1 + kx; if ((unsigned)ix >= 64u) continue;
      #pragma unroll
      for (int ci = 0; ci < 4; ci++){
        float v = lrelu(fmaf(ip[ci * 4096 + iy * 64 + ix], scv[ci], shv[ci]));
        const float* wp = w + ((coq * 4) * 4 + ci) * 9 + ky * 3 + kx;
        a0 = fmaf(v, wp[0], a0);
        a1 = fmaf(v, wp[36], a1);
        a2 = fmaf(v, wp[72], a2);
        a3 = fmaf(v, wp[108], a3);
      }
    }
  }
  float4 o; o.x = a0; o.y = a1; o.z = a2; o.w = a3;
  ((float4*)Zq)[coq * 65536 + sp] = o;
}

// ---------------- prep_all: blocks 0-3 VQ codebook prep, blocks 4-39 postq P-table ----------------
__global__ __launch_bounds__(256) void prep_all(const float* __restrict__ cb, double* __restrict__ cb64,
    double* __restrict__ cbn64, float* __restrict__ cbn32, unsigned short* __restrict__ cbh,
    unsigned short* __restrict__ cbl, int* __restrict__ flagcnt,
    const float* __restrict__ pw, float* __restrict__ P){
  int t = threadIdx.x;
  if (blockIdx.x < 4){
    int k = blockIdx.x * 256 + t;
    if (k == 0) flagcnt[0] = 0;
    double s = 0;
    for (int d = 0; d < 64; d++){
      float v = cb[k * 64 + d];
      cb64[(size_t)k * 64 + d] = (double)v;
      s = fma((double)v, (double)v, s);
      unsigned h = bf16rne(v);
      float hf = __uint_as_float(h << 16);
      unsigned l = bf16rne(v - hf);
      cbh[k * 64 + d] = (unsigned short)h;
      cbl[k * 64 + d] = (unsigned short)l;
    }
    cbn64[k] = s;
    cbn32[k] = (float)s;
  } else {
    int gid = (blockIdx.x - 4) * 256 + t;
    if (gid >= 9216) return;
    int k = gid / 9, tap = gid - k * 9;
    float a0 = 0.f, a1 = 0.f, a2 = 0.f, a3 = 0.f;
    const float* cp = cb + (k << 6);
    #pragma unroll 16
    for (int ci = 0; ci < 64; ci++){
      float c = cp[ci];
      a0 = fmaf(c, pw[(0 * 64 + ci) * 9 + tap], a0);
      a1 = fmaf(c, pw[(1 * 64 + ci) * 9 + tap], a1);
      a2 = fmaf(c, pw[(2 * 64 + ci) * 9 + tap], a2);
      a3 = fmaf(c, pw[(3 * 64 + ci) * 9 + tap], a3);
    }
    float4 o; o.x = a0; o.y = a1; o.z = a2; o.w = a3;
    ((float4*)P)[gid] = o;
  }
}

// ---------------- VQ screen via MFMA: per-step (128-code) partial bests + global merge ----------------
__global__ __launch_bounds__(256) void vq_screen_mfma(const float* __restrict__ Zq,
    const unsigned short* __restrict__ cbh, const unsigned short* __restrict__ cbl,
    const float* __restrict__ cbn32, int* __restrict__ idxout,
    int* __restrict__ flagcnt, int* __restrict__ flaglist, float* __restrict__ stepb){
  __shared__ unsigned short lcb[32 * 64 * 8];
  __shared__ float lcn[128];
  int t = threadIdx.x;
  int lane = t & 63;
  int w = t >> 6;
  int col = lane & 15, hg = lane >> 4;
  int pos0 = blockIdx.x * 128 + w * 32;
  int posA = pos0 + col, posB = pos0 + 16 + col;
  const float4* Zq4 = (const float4*)Zq;
  short8x zhA[2], zlA[2], zhB[2], zlB[2];
  #pragma unroll
  for (int kc = 0; kc < 2; kc++){
    #pragma unroll
    for (int tb = 0; tb < 2; tb++){
      int pos = tb ? posB : posA;
      float4 f0 = Zq4[(size_t)(8 * kc + 2 * hg) * 65536 + pos];
      float4 f1 = Zq4[(size_t)(8 * kc + 2 * hg + 1) * 65536 + pos];
      float zv[8] = {f0.x, f0.y, f0.z, f0.w, f1.x, f1.y, f1.z, f1.w};
      union { unsigned u[4]; short8x v; } H, L;
      #pragma unroll
      for (int j = 0; j < 4; j++){
        unsigned h0 = bf16rne(zv[2 * j]);
        unsigned h1 = bf16rne(zv[2 * j + 1]);
        float hf0 = __uint_as_float(h0 << 16);
        float hf1 = __uint_as_float(h1 << 16);
        unsigned l0 = bf16rne(zv[2 * j] - hf0);
        unsigned l1 = bf16rne(zv[2 * j + 1] - hf1);
        H.u[j] = h0 | (h1 << 16);
        L.u[j] = l0 | (l1 << 16);
      }
      if (tb){ zhB[kc] = H.v; zlB[kc] = L.v; } else { zhA[kc] = H.v; zlA[kc] = L.v; }
    }
  }
  float BA = 3.0e38f, SA = 3.0e38f, BB = 3.0e38f, SBt = 3.0e38f;
  int IA = 0, IB = 0;
  for (int step = 0; step < 8; step++){
    int code0 = step * 128;
    __syncthreads();
    #pragma unroll
    for (int i = 0; i < 8; i++){
      int piece = i * 256 + t;
      int fb = piece >> 6, pl = piece & 63;
      int g = fb >> 2, kc = (fb >> 1) & 1, sp = fb & 1;
      const unsigned short* src = (sp ? cbl : cbh)
          + ((size_t)(code0 + g * 16 + (pl & 15)) << 6) + kc * 32 + ((pl >> 4) << 3);
      *(uint4*)&lcb[piece * 8] = *(const uint4*)src;
    }
    if (t < 128) lcn[t] = cbn32[code0 + t];
    __syncthreads();
    float bA = 3.0e38f, sA = 3.0e38f, bB = 3.0e38f, sB = 3.0e38f;
    int iA = 0, iB = 0;
    #pragma unroll 2
    for (int g = 0; g < 8; g++){
      const short8x* lc8 = (const short8x*)lcb;
      short8x Ah0 = lc8[(g * 4 + 0) * 64 + lane];
      short8x Al0 = lc8[(g * 4 + 1) * 64 + lane];
      short8x Ah1 = lc8[(g * 4 + 2) * 64 + lane];
      short8x Al1 = lc8[(g * 4 + 3) * 64 + lane];
      f32x4 accA = {0.f, 0.f, 0.f, 0.f};
      f32x4 accB = {0.f, 0.f, 0.f, 0.f};
      accA = __builtin_amdgcn_mfma_f32_16x16x32_bf16(Ah0, zhA[0], accA, 0, 0, 0);
      accA = __builtin_amdgcn_mfma_f32_16x16x32_bf16(Ah1, zhA[1], accA, 0, 0, 0);
      accA = __builtin_amdgcn_mfma_f32_16x16x32_bf16(Ah0, zlA[0], accA, 0, 0, 0);
      accA = __builtin_amdgcn_mfma_f32_16x16x32_bf16(Ah1, zlA[1], accA, 0, 0, 0);
      accA = __builtin_amdgcn_mfma_f32_16x16x32_bf16(Al0, zhA[0], accA, 0, 0, 0);
      accA = __builtin_amdgcn_mfma_f32_16x16x32_bf16(Al1, zhA[1], accA, 0, 0, 0);
      accB = __builtin_amdgcn_mfma_f32_16x16x32_bf16(Ah0, zhB[0], accB, 0, 0, 0);
      accB = __builtin_amdgcn_mfma_f32_16x16x32_bf16(Ah1, zhB[1], accB, 0, 0, 0);
      accB = __builtin_amdgcn_mfma_f32_16x16x32_bf16(Ah0, zlB[0], accB, 0, 0, 0);
      accB = __builtin_amdgcn_mfma_f32_16x16x32_bf16(Ah1, zlB[1], accB, 0, 0, 0);
      accB = __builtin_amdgcn_mfma_f32_16x16x32_bf16(Al0, zhB[0], accB, 0, 0, 0);
      accB = __builtin_amdgcn_mfma_f32_16x16x32_bf16(Al1, zhB[1], accB, 0, 0, 0);
      int cbase = code0 + g * 16 + 4 * hg;
      #pragma unroll
      for (int r = 0; r < 4; r++){
        float cn = lcn[g * 16 + 4 * hg + r];
        float vA = fmaf(accA[r], -2.0f, cn);
        sA = fminf(sA, fmaxf(vA, bA));
        if (vA < bA){ bA = vA; iA = cbase + r; }
        float vB = fmaf(accB[r], -2.0f, cn);
        sB = fminf(sB, fmaxf(vB, bB));
        if (vB < bB){ bB = vB; iB = cbase + r; }
      }
    }
    #pragma unroll
    for (int off = 16; off <= 32; off <<= 1){
      float ob = __shfl_xor(bA, off);
      float os = __shfl_xor(sA, off);
      int oi = __shfl_xor(iA, off);
      sA = fminf(fminf(sA, os), fmaxf(bA, ob));
      if (ob < bA){ bA = ob; iA = oi; }
      ob = __shfl_xor(bB, off);
      os = __shfl_xor(sB, off);
      oi = __shfl_xor(iB, off);
      sB = fminf(fminf(sB, os), fmaxf(bB, ob));
      if (ob < bB){ bB = ob; iB = oi; }
    }
    if (hg == 0){
      stepb[step * 65536 + posA] = bA;
      stepb[step * 65536 + posB] = bB;
    }
    if (bA < BA){ SA = fminf(BA, sA); BA = bA; IA = iA; } else SA = fminf(SA, bA);
    if (bB < BB){ SBt = fminf(BB, sB); BB = bB; IB = iB; } else SBt = fminf(SBt, bB);
  }
  if (hg == 0){
    idxout[posA] = IA;
    if (SA - BA < 1.2e-2f){
      int slot = atomicAdd(flagcnt, 1);
      flaglist[slot] = posA;
    }
    idxout[posB] = IB;
    if (SBt - BB < 1.2e-2f){
      int slot = atomicAdd(flagcnt, 1);
      flaglist[slot] = posB;
    }
  }
}

// ---------------- VQ refine: exact f64 re-rank over candidate steps only ----------------
__global__ __launch_bounds__(256) void vq_refine(const float* __restrict__ Zq, const double* __restrict__ cb64,
    const double* __restrict__ cbn64, const int* __restrict__ flagcnt, const int* __restrict__ flaglist,
    const float* __restrict__ stepb, int* __restrict__ idxout){
  int gw = (blockIdx.x * 256 + threadIdx.x) >> 6;
  int lane = threadIdx.x & 63;
  int nf = flagcnt[0];
  for (int f = gw; f < nf; f += 512){
    int pos = flaglist[f];
    float zr[64];
    #pragma unroll
    for (int q = 0; q < 16; q++){
      float4 v = ((const float4*)Zq)[q * 65536 + pos];
      zr[4 * q] = v.x; zr[4 * q + 1] = v.y; zr[4 * q + 2] = v.z; zr[4 * q + 3] = v.w;
    }
    float sb[8];
    float B = 3.0e38f;
    #pragma unroll
    for (int s = 0; s < 8; s++){ sb[s] = stepb[s * 65536 + pos]; B = fminf(B, sb[s]); }
    float lim = B + 1.2e-2f;
    double best = 1e300; int bi = 1 << 30;
    #pragma unroll
    for (int s = 0; s < 8; s++){
      if (sb[s] < lim){
        int k0 = s * 128 + 2 * lane;
        #pragma unroll
        for (int kk = 0; kk < 2; kk++){
          int k = k0 + kk;
          const double* c = cb64 + (size_t)k * 64;
          double a0 = 0, a1 = 0, a2 = 0, a3 = 0;
          #pragma unroll
          for (int d = 0; d < 64; d += 4){
            a0 = fma(c[d], (double)zr[d], a0);
            a1 = fma(c[d + 1], (double)zr[d + 1], a1);
            a2 = fma(c[d + 2], (double)zr[d + 2], a2);
            a3 = fma(c[d + 3], (double)zr[d + 3], a3);
          }
          double sc = cbn64[k] - 2.0 * ((a0 + a1) + (a2 + a3));
          if (sc < best){ best = sc; bi = k; }
        }
      }
    }
    #pragma unroll
    for (int o = 32; o > 0; o >>= 1){
      double ob = __shfl_xor(best, o);
      int oi = __shfl_xor(bi, o);
      if (ob < best || (ob == best && oi < bi)){ best = ob; bi = oi; }
    }
    if (lane == 0) idxout[pos] = bi;
  }
}

// ---------------- postq gather: out[pos][co] = bias + sum_tap P[idx[nbr]][tap][co]; fused loss ----------------
__global__ __launch_bounds__(256) void postq_gather(const float* __restrict__ P, const int* __restrict__ idxm,
    const float* __restrict__ bias, float* __restrict__ out,
    const float* __restrict__ Zq, const float* __restrict__ cb, double* __restrict__ losspart){
  int gid = blockIdx.x * 256 + threadIdx.x;
  int sp = gid & 65535;
  int co = gid >> 16;
  co = __builtin_amdgcn_readfirstlane(co);
  int xx = sp & 63, yy = (sp >> 6) & 63, n = sp >> 12;
  float acc = bias[co];
  #pragma unroll
  for (int ky = 0; ky < 3; ky++){
    int iy = yy - 1 + ky; if ((unsigned)iy >= 64u) continue;
    #pragma unroll
    for (int kx = 0; kx < 3; kx++){
      int ix = xx - 1 + kx; if ((unsigned)ix >= 64u) continue;
      int spt = (n << 12) + (iy << 6) + ix;
      int k = idxm[spt];
      acc += P[(k * 9 + (ky * 3 + kx)) * 4 + co];
    }
  }
  out[((size_t)(n * 4 + co) << 12) + (yy << 6) + xx] = acc;
  if (co == 0){
    int k = idxm[sp];
    const float4* c4 = (const float4*)(cb + (k << 6));
    double l = 0;
    #pragma unroll
    for (int q = 0; q < 16; q++){
      float4 z = ((const float4*)Zq)[q * 65536 + sp];
      float4 c = c4[q];
      float d0 = z.x - c.x, d1 = z.y - c.y, d2 = z.z - c.z, d3 = z.w - c.w;
      l += (double)d0 * d0 + (double)d1 * d1 + (double)d2 * d2 + (double)d3 * d3;
    }
    __shared__ double sb[256];
    int t = threadIdx.x;
    sb[t] = l; __syncthreads();
    for (int o = 128; o > 0; o >>= 1){
      if (t < o) sb[t] += sb[t + o];
      __syncthreads();
    }
    if (t == 0) losspart[blockIdx.x] = sb[0];
  }
}

// ---------------- transposed conv k3 s2 p1 op1, 8 co/thread, optional input-BN, fused stats ----------------
template<int CI, int CO, int IHt, int IWt, bool APPLY>
__global__ __launch_bounds__(256) void convT_cob8(const float* __restrict__ in, const float* __restrict__ w,
    const float* __restrict__ bias, const float* __restrict__ ssIn, float* __restrict__ out,
    double* __restrict__ part){
  constexpr int SB = IHt * IWt / 256;
  constexpr int COG = CO / 8;
  constexpr int P = 16 * SB;
  const int OW = IWt * 2;
  int idx = blockIdx.x * 256 + threadIdx.x;
  int ix = idx % IWt, iy = (idx / IWt) % IHt;
  int cog = (idx / (IWt * IHt)) % COG, n = idx / (IWt * IHt * COG);
  cog = __builtin_amdgcn_readfirstlane(cog);
  n   = __builtin_amdgcn_readfirstlane(n);
  float a00[8], a01[8], a10[8], a11[8];
  #pragma unroll
  for (int j = 0; j < 8; j++){ float b = bias[cog * 8 + j]; a00[j] = b; a01[j] = b; a10[j] = b; a11[j] = b; }
  bool okx = (ix + 1 < IWt), oky = (iy + 1 < IHt);
  int ixp = okx ? ix + 1 : ix, iyp = oky ? iy + 1 : iy;
  const float* ip = in + (size_t)n * CI * IHt * IWt;
  #pragma unroll 4
  for (int ci = 0; ci < CI; ci++){
    const float* p = ip + ci * IHt * IWt;
    float v00 = p[iy * IWt + ix];
    float v01 = p[iy * IWt + ixp];
    float v10 = p[iyp * IWt + ix];
    float v11 = p[iyp * IWt + ixp];
    if (APPLY){
      float sc = ssIn[ci], sh = ssIn[CI + ci];
      v00 = lrelu(fmaf(v00, sc, sh));
      v01 = lrelu(fmaf(v01, sc, sh));
      v10 = lrelu(fmaf(v10, sc, sh));
      v11 = lrelu(fmaf(v11, sc, sh));
    }
    if (!okx) v01 = 0.f;
    if (!oky) v10 = 0.f;
    if (!(okx && oky)) v11 = 0.f;
    const float* wp = w + ((size_t)ci * CO + cog * 8) * 9;
    #pragma unroll
    for (int j = 0; j < 8; j++){
      const float* q = wp + j * 9;
      a00[j] = fmaf(q[4], v00, a00[j]);
      a01[j] = fmaf(q[3], v01, a01[j]); a01[j] = fmaf(q[5], v00, a01[j]);
      a10[j] = fmaf(q[1], v10, a10[j]); a10[j] = fmaf(q[7], v00, a10[j]);
      a11[j] = fmaf(q[0], v11, a11[j]); a11[j] = fmaf(q[2], v10, a11[j]);
      a11[j] = fmaf(q[6], v01, a11[j]); a11[j] = fmaf(q[8], v00, a11[j]);
    }
  }
  float sums[8], sqs[8];
  #pragma unroll
  for (int j = 0; j < 8; j++){
    float* o = out + (((size_t)n * CO + cog * 8 + j) * (IHt * 2) + 2 * iy) * OW + 2 * ix;
    float2 r0; r0.x = a00[j]; r0.y = a01[j];
    float2 r1; r1.x = a10[j]; r1.y = a11[j];
    *(float2*)o = r0;
    *(float2*)(o + OW) = r1;
    sums[j] = (a00[j] + a01[j]) + (a10[j] + a11[j]);
    sqs[j] = (a00[j] * a00[j] + a01[j] * a01[j]) + (a10[j] * a10[j] + a11[j] * a11[j]);
  }
  __shared__ float sred[256 * 17];
  int sb = blockIdx.x % SB;
  stats_epilogue<8>(sums, sqs, part, cog * 8, P, n * SB + sb, sred);
}

// ---------------- d3: 32->3 @256x256, LDS-tiled (24 KB), shfl halo, fused bn4 + loss write ----------------
__global__ __launch_bounds__(256) void d3_tile(const float* __restrict__ F, const float* __restrict__ w,
    const float* __restrict__ bias, const float* __restrict__ ss, float* __restrict__ out,
    const double* __restrict__ losspart){
  __shared__ float st[4 * 6 * 256];
  int t = threadIdx.x;
  int xg = t & 63, r = t >> 6;
  int n = blockIdx.x >> 6, oyb = blockIdx.x & 63;
  int oy = oyb * 4 + r;
  if (blockIdx.x == 0 && t < 64){
    double s = losspart[t] + losspart[t + 64] + losspart[t + 128] + losspart[t + 192];
    #pragma unroll
    for (int o = 32; o > 0; o >>= 1) s += __shfl_xor(s, o);
    if (t == 0) out[3145728] = (float)(1.25 * s / (65536.0 * 64.0));
  }
  float acc[3][4];
  #pragma unroll
  for (int co = 0; co < 3; co++){
    float b = bias[co];
    #pragma unroll
    for (int j = 0; j < 4; j++) acc[co][j] = b;
  }
  const float* base = F + (size_t)n * 32 * 65536;
  for (int cc = 0; cc < 8; cc++){
    int cib = cc * 4;
    #pragma unroll
    for (int j = 0; j < 6; j++){
      int p = j * 256 + t;
      int cl = p / 384, rem = p - cl * 384;
      int rr = rem >> 6, xq = rem & 63;
      int g = oyb * 4 - 1 + rr;
      float4 v;
      if ((unsigned)g < 256u){
        v = *(const float4*)(base + ((size_t)(cib + cl) * 256 + g) * 256 + 4 * xq);
        float sc = ss[cib + cl], sh = ss[32 + cib + cl];
        v.x = lrelu(fmaf(v.x, sc, sh));
        v.y = lrelu(fmaf(v.y, sc, sh));
        v.z = lrelu(fmaf(v.z, sc, sh));
        v.w = lrelu(fmaf(v.w, sc, sh));
      } else {
        v.x = 0.f; v.y = 0.f; v.z = 0.f; v.w = 0.f;
      }
      *(float4*)&st[((cl * 6 + rr) << 8) | (4 * xq)] = v;
    }
    __syncthreads();
    #pragma unroll
    for (int cl = 0; cl < 4; cl++){
      #pragma unroll
      for (int ky = 0; ky < 3; ky++){
        int rr = r + ky;
        float4 A = *(const float4*)&st[((cl * 6 + rr) << 8) | (4 * xg)];
        float Lv = __shfl_up(A.w, 1);
        float Rv = __shfl_down(A.x, 1);
        float u0 = (xg == 0) ? 0.f : Lv;
        float u5 = (xg == 63) ? 0.f : Rv;
        float u[6] = {u0, A.x, A.y, A.z, A.w, u5};
        #pragma unroll
        for (int co = 0; co < 3; co++){
          const float* wp = w + ((co * 32 + cib + cl) * 9) + ky * 3;
          #pragma unroll
          for (int j = 0; j < 4; j++){
            acc[co][j] = fmaf(u[j],     wp[0], acc[co][j]);
            acc[co][j] = fmaf(u[j + 1], wp[1], acc[co][j]);
            acc[co][j] = fmaf(u[j + 2], wp[2], acc[co][j]);
          }
        }
      }
    }
    __syncthreads();
  }
  #pragma unroll
  for (int co = 0; co < 3; co++){
    float4 s0;
    s0.x = tanh_fast(acc[co][0]); s0.y = tanh_fast(acc[co][1]);
    s0.z = tanh_fast(acc[co][2]); s0.w = tanh_fast(acc[co][3]);
    float* o = out + ((size_t)(n * 3 + co) * 256 + oy) * 256 + 4 * xg;
    *(float4*)o = s0;
  }
}

// ---------------- launch ----------------
extern "C" void kernel_launch(void* const* d_in, const int* in_sizes, int n_in,
                              void* d_out, int out_size, void* d_ws, size_t ws_size,
                              hipStream_t stream){
  const float* x      = (const float*)d_in[0];
  const float* cb     = (const float*)d_in[1];
  const float* e1_w   = (const float*)d_in[2];
  const float* e1_b   = (const float*)d_in[3];
  const float* bn1_g  = (const float*)d_in[4];
  const float* bn1_b  = (const float*)d_in[5];
  const float* e2_w   = (const float*)d_in[6];
  const float* e2_b   = (const float*)d_in[7];
  const float* bn2_g  = (const float*)d_in[8];
  const float* bn2_b  = (const float*)d_in[9];
  const float* preq_w = (const float*)d_in[10];
  const float* preq_b = (const float*)d_in[11];
  const float* postq_w= (const float*)d_in[12];
  const float* postq_b= (const float*)d_in[13];
  const float* d1_w   = (const float*)d_in[14];
  const float* d1_b   = (const float*)d_in[15];
  const float* bn3_g  = (const float*)d_in[16];
  const float* bn3_b  = (const float*)d_in[17];
  const float* d2_w   = (const float*)d_in[18];
  const float* d2_b   = (const float*)d_in[19];
  const float* bn4_g  = (const float*)d_in[20];
  const float* bn4_b  = (const float*)d_in[21];
  const float* d3_w   = (const float*)d_in[22];
  const float* d3_b   = (const float*)d_in[23];
  float* out = (float*)d_out;
  char* ws = (char*)d_ws;

  double* losspart = (double*)ws;                        // 2048 B
  int*    flagcnt  = (int*)(ws + 2048);
  float*  ss       = (float*)(ws + 4096);
  double* cb64     = (double*)(ws + 8192);               // 512 KB
  double* cbn64    = (double*)(ws + 532480);             // 8 KB
  float*  cbn32    = (float*)(ws + 540672);              // 4 KB
  unsigned short* cbh = (unsigned short*)(ws + 544768);  // 128 KB
  unsigned short* cbl = (unsigned short*)(ws + 675840);  // 128 KB
  int*    flaglist = (int*)(ws + 806912);                // 256 KB
  int*    idx      = (int*)(ws + 1069056);               // 256 KB
  double* part_e1  = (double*)(ws + 1331200);            // 128 KB
  double* part_e2  = (double*)(ws + 1462272);            // 16 KB
  float*  Ptab     = (float*)(ws + 1478656);             // 147 KB (aliases part_d1; dead before d1 writes)
  double* part_d1  = (double*)(ws + 1478656);            // 64 KB
  float*  A        = (float*)(ws + 2097152);             // 16.78 MB
  float*  B        = (float*)(ws + 18874368);            // 1 MB
  float*  Zq       = (float*)(ws + 19922944);            // 16.78 MB
  double* part_d2  = (double*)(ws + 19922944);           // 512 KB, aliases Zq (dead after postq_gather)
  float*  F        = (float*)(ws + 36700160);            // 134.2 MB
  float*  stepb    = (float*)(ws + 36700160);            // 2 MB, aliases F head (dead before d2 writes F)

  float *ss1 = ss + 0, *ss2 = ss + 32, *ss3 = ss + 48, *ss4 = ss + 80;
  float* D = B;   // B dead after preq

  prep_all<<<40, 256, 0, stream>>>(cb, cb64, cbn64, cbn32, cbh, cbl, flagcnt, postq_w, Ptab);

  // encoder
  e1_conv<<<1024, 256, 0, stream>>>(x, e1_w, e1_b, A, part_e1);
  bn_red_fin<<<16, 256, 0, stream>>>(part_e1, 512, bn1_g, bn1_b, ss1, 16, 262144.0);
  e2_conv<<<1024, 256, 0, stream>>>(A, e2_w, e2_b, ss1, B, part_e2);
  bn_red_fin<<<4, 256, 0, stream>>>(part_e2, 256, bn2_g, bn2_b, ss2, 4, 65536.0);
  preq_conv<<<4096, 256, 0, stream>>>(B, preq_w, preq_b, ss2, Zq);

  // VQ
  vq_screen_mfma<<<512, 256, 0, stream>>>(Zq, cbh, cbl, cbn32, idx, flagcnt, flaglist, stepb);
  vq_refine<<<128, 256, 0, stream>>>(Zq, cb64, cbn64, flagcnt, flaglist, stepb, idx);

  // decoder (postq_gather also computes VQ loss partials; Zq dead after this)
  postq_gather<<<1024, 256, 0, stream>>>(Ptab, idx, postq_b, D, Zq, cb, losspart);
  convT_cob8<4, 16, 64, 64, false><<<512, 256, 0, stream>>>(D, d1_w, d1_b, nullptr, A, part_d1);
  bn_red_fin<<<16, 256, 0, stream>>>(part_d1, 256, bn3_g, bn3_b, ss3, 16, 262144.0);
  convT_cob8<16, 32, 128, 128, true><<<4096, 256, 0, stream>>>(A, d2_w, d2_b, ss3, F, part_d2);
  bn_red_fin<<<32, 256, 0, stream>>>(part_d2, 1024, bn4_g, bn4_b, ss4, 32, 1048576.0);
  d3_tile<<<1024, 256, 0, stream>>>(F, d3_w, d3_b, ss4, out, losspart);
}

// Round 13
// 259.316 us; speedup vs baseline: 1.1219x; 1.0540x over previous
//
#include <hip/hip_runtime.h>
#include <math.h>

#define EPSV 1e-5
#define SLOPE 0.1f

typedef __attribute__((ext_vector_type(4))) float f32x4;
typedef __attribute__((ext_vector_type(8))) short short8x;

__device__ __forceinline__ float lrelu(float x){ return fmaxf(x, SLOPE * x); }
__device__ __forceinline__ float tanh_fast(float x){
  float e = __expf(2.f * x);
  return 1.f - 2.f / (e + 1.f);
}
__device__ __forceinline__ unsigned bf16rne(float f){
  unsigned u = __float_as_uint(f);
  u += 0x7fff + ((u >> 16) & 1);
  return u >> 16;
}

// ---- block BN-stats epilogue: per-thread CL channel sums/sqs -> f64 partials (padded stride) ----
template<int CL>
__device__ __forceinline__ void stats_epilogue(const float* sums, const float* sqs,
    double* __restrict__ part, int chbase, int P, int p, float* sred){
  const int C2 = 2 * CL;
  const int ST = C2 + 1;
  int t = threadIdx.x;
  #pragma unroll
  for (int c = 0; c < CL; c++){
    sred[t * ST + c] = sums[c];
    sred[t * ST + CL + c] = sqs[c];
  }
  __syncthreads();
  if (t < 64){
    int c = t % C2;
    int g = t / C2;
    const int G = 64 / C2;
    const int R = 256 / G;
    double s = 0;
    for (int r = g * R; r < (g + 1) * R; r++) s += (double)sred[r * ST + c];
    #pragma unroll
    for (int off = C2; off < 64; off <<= 1) s += __shfl_xor(s, off);
    if (t < C2){
      int ch = chbase + (c < CL ? c : c - CL);
      part[(size_t)ch * 2 * P + (c < CL ? 0 : P) + p] = s;
    }
  }
}

// ---- reduce partials + finalize scale/shift ----
__global__ __launch_bounds__(256) void bn_red_fin(const double* __restrict__ part, int P,
    const float* __restrict__ g, const float* __restrict__ b, float* __restrict__ ss, int C, double count){
  int c = blockIdx.x;
  __shared__ double r0[256], r1[256];
  int t = threadIdx.x;
  double s = 0, q = 0;
  for (int p = t; p < P; p += 256){
    s += part[(size_t)c * 2 * P + p];
    q += part[(size_t)c * 2 * P + P + p];
  }
  r0[t] = s; r1[t] = q; __syncthreads();
  for (int o = 128; o > 0; o >>= 1){
    if (t < o){ r0[t] += r0[t + o]; r1[t] += r1[t + o]; }
    __syncthreads();
  }
  if (t == 0){
    double m = r0[0] / count;
    double var = r1[0] / count - m * m;
    double scale = (double)g[c] / sqrt(var + EPSV);
    ss[c] = (float)scale;
    ss[C + c] = (float)((double)b[c] - m * scale);
  }
}

// ---------------- e1 (+fused prep in blocks >= 1024): 3->16 s2, co-split x2, bn1-stats ----------------
__global__ __launch_bounds__(256) void e1_conv(const float* __restrict__ x, const float* __restrict__ w,
    const float* __restrict__ bias, float* __restrict__ out, double* __restrict__ part,
    const float* __restrict__ cb, double* __restrict__ cb64, double* __restrict__ cbn64,
    float* __restrict__ cbn32, unsigned short* __restrict__ cbh, unsigned short* __restrict__ cbl,
    int* __restrict__ flagcnt, const float* __restrict__ pw, float* __restrict__ P){
  if (blockIdx.x >= 1024){
    int pb = blockIdx.x - 1024;     // 0..39
    int t = threadIdx.x;
    if (pb < 4){
      int k = pb * 256 + t;
      if (k == 0) flagcnt[0] = 0;
      double s = 0;
      for (int d = 0; d < 64; d++){
        float v = cb[k * 64 + d];
        cb64[(size_t)k * 64 + d] = (double)v;
        s = fma((double)v, (double)v, s);
        unsigned h = bf16rne(v);
        float hf = __uint_as_float(h << 16);
        unsigned l = bf16rne(v - hf);
        cbh[k * 64 + d] = (unsigned short)h;
        cbl[k * 64 + d] = (unsigned short)l;
      }
      cbn64[k] = s;
      cbn32[k] = (float)s;
    } else {
      int gid = (pb - 4) * 256 + t;
      if (gid >= 9216) return;
      int k = gid / 9, tap = gid - k * 9;
      float a0 = 0.f, a1 = 0.f, a2 = 0.f, a3 = 0.f;
      const float* cp = cb + (k << 6);
      #pragma unroll 16
      for (int ci = 0; ci < 64; ci++){
        float c = cp[ci];
        a0 = fmaf(c, pw[(0 * 64 + ci) * 9 + tap], a0);
        a1 = fmaf(c, pw[(1 * 64 + ci) * 9 + tap], a1);
        a2 = fmaf(c, pw[(2 * 64 + ci) * 9 + tap], a2);
        a3 = fmaf(c, pw[(3 * 64 + ci) * 9 + tap], a3);
      }
      float4 o; o.x = a0; o.y = a1; o.z = a2; o.w = a3;
      ((float4*)P)[gid] = o;
    }
    return;
  }
  int idx = blockIdx.x * 256 + threadIdx.x;
  int ox2 = idx & 63, oy = (idx >> 6) & 127;
  int cog = (idx >> 13) & 1, n = idx >> 14;
  cog = __builtin_amdgcn_readfirstlane(cog);
  n   = __builtin_amdgcn_readfirstlane(n);
  float acc[8][2];
  #pragma unroll
  for (int co = 0; co < 8; co++){ float b = bias[cog * 8 + co]; acc[co][0] = b; acc[co][1] = b; }
  int ix0 = 4 * ox2 - 1;
  int lclamp = (ox2 > 0) ? ix0 : 0;
  const float* xp = x + (size_t)n * 3 * 65536;
  #pragma unroll
  for (int ci = 0; ci < 3; ci++){
    const float* pl = xp + ci * 65536;
    #pragma unroll
    for (int ky = 0; ky < 3; ky++){
      int iy = 2 * oy - 1 + ky;
      if (iy >= 0){
        const float* row = pl + iy * 256;
        float l = row[lclamp];
        float4 m = *(const float4*)(row + ix0 + 1);
        float v0 = (ox2 > 0) ? l : 0.f;
        #pragma unroll
        for (int co = 0; co < 8; co++){
          const float* wp = w + (((cog * 8 + co) * 3 + ci) * 3 + ky) * 3;
          acc[co][0] = fmaf(v0,  wp[0], acc[co][0]);
          acc[co][0] = fmaf(m.x, wp[1], acc[co][0]);
          acc[co][0] = fmaf(m.y, wp[2], acc[co][0]);
          acc[co][1] = fmaf(m.y, wp[0], acc[co][1]);
          acc[co][1] = fmaf(m.z, wp[1], acc[co][1]);
          acc[co][1] = fmaf(m.w, wp[2], acc[co][1]);
        }
      }
    }
  }
  float sums[8], sqs[8];
  #pragma unroll
  for (int co = 0; co < 8; co++){
    float2 st; st.x = acc[co][0]; st.y = acc[co][1];
    *(float2*)(out + ((size_t)(n * 16 + cog * 8 + co) * 128 + oy) * 128 + 2 * ox2) = st;
    sums[co] = acc[co][0] + acc[co][1];
    sqs[co] = acc[co][0] * acc[co][0] + acc[co][1] * acc[co][1];
  }
  __shared__ float sred[256 * 17];
  int p = ((blockIdx.x >> 6) << 5) + (blockIdx.x & 31);
  stats_epilogue<8>(sums, sqs, part, cog * 8, 512, p, sred);
}

// ---------------- e2: 16->4 s2, co-split x4 (1 co/thread), fused bn1-apply + bn2-stats ----------------
__global__ __launch_bounds__(256) void e2_conv(const float* __restrict__ in, const float* __restrict__ w,
    const float* __restrict__ bias, const float* __restrict__ ssIn, float* __restrict__ out,
    double* __restrict__ part){
  int gid = blockIdx.x * 256 + threadIdx.x;
  int sp = gid & 65535;
  int co = gid >> 16;
  co = __builtin_amdgcn_readfirstlane(co);
  int ox = sp & 63, oy = (sp >> 6) & 63, n = sp >> 12;
  float acc = bias[co];
  int iy0 = oy * 2 - 1, ix0 = ox * 2 - 1;
  const float* ip = in + (size_t)n * 16 * 16384;
  const float* wb = w + co * 144;
  #pragma unroll
  for (int ky = 0; ky < 3; ky++){
    int iy = iy0 + ky; if ((unsigned)iy >= 128u) continue;
    #pragma unroll
    for (int kx = 0; kx < 3; kx++){
      int ix = ix0 + kx; if ((unsigned)ix >= 128u) continue;
      const float* r = ip + iy * 128 + ix;
      #pragma unroll
      for (int ci = 0; ci < 16; ci++){
        float v = lrelu(fmaf(r[ci * 16384], ssIn[ci], ssIn[16 + ci]));
        acc = fmaf(v, wb[ci * 9 + ky * 3 + kx], acc);
      }
    }
  }
  out[(((size_t)n * 4 + co) * 64 + oy) * 64 + ox] = acc;
  __shared__ double s0[256], s1[256];
  int t = threadIdx.x;
  s0[t] = (double)acc;
  s1[t] = (double)acc * (double)acc;
  __syncthreads();
  for (int o = 128; o > 0; o >>= 1){
    if (t < o){ s0[t] += s0[t + o]; s1[t] += s1[t + o]; }
    __syncthreads();
  }
  if (t == 0){
    int p = blockIdx.x & 255;
    part[(size_t)co * 512 + p] = s0[0];
    part[(size_t)co * 512 + 256 + p] = s1[0];
  }
}

// ---------------- preq: fused bn2-apply, output plane layout Zq[coq][pos][4] ----------------
__global__ __launch_bounds__(256) void preq_conv(const float* __restrict__ in, const float* __restrict__ w,
    const float* __restrict__ bias, const float* __restrict__ ssIn, float* __restrict__ Zq){
  int idx = blockIdx.x * 256 + threadIdx.x;
  int sp = idx & 65535;
  int coq = idx >> 16;
  int x = sp & 63, y = (sp >> 6) & 63, n = sp >> 12;
  float scv[4] = {ssIn[0], ssIn[1], ssIn[2], ssIn[3]};
  float shv[4] = {ssIn[4], ssIn[5], ssIn[6], ssIn[7]};
  float a0 = bias[coq * 4 + 0], a1 = bias[coq * 4 + 1], a2 = bias[coq * 4 + 2], a3 = bias[coq * 4 + 3];
  const float* ip = in + (size_t)n * 4 * 4096;
  #pragma unroll
  for (int ky = 0; ky < 3; ky++){
    int iy = y - 1 + ky; if ((unsigned)iy >= 64u) continue;
    #pragma unroll
    for (int kx = 0; kx < 3; kx++){
      int ix = x - 1 + kx; if ((unsigned)ix >= 64u) continue;
      #pragma unroll
      for (int ci = 0; ci < 4; ci++){
        float v = lrelu(fmaf(ip[ci * 4096 + iy * 64 + ix], scv[ci], shv[ci]));
        const float* wp = w + ((coq * 4) * 4 + ci) * 9 + ky * 3 + kx;
        a0 = fmaf(v, wp[0], a0);
        a1 = fmaf(v, wp[36], a1);
        a2 = fmaf(v, wp[72], a2);
        a3 = fmaf(v, wp[108], a3);
      }
    }
  }
  float4 o; o.x = a0; o.y = a1; o.z = a2; o.w = a3;
  ((float4*)Zq)[coq * 65536 + sp] = o;
}

// ---------------- VQ screen via MFMA: per-step (128-code) partial bests + global merge ----------------
__global__ __launch_bounds__(256) void vq_screen_mfma(const float* __restrict__ Zq,
    const unsigned short* __restrict__ cbh, const unsigned short* __restrict__ cbl,
    const float* __restrict__ cbn32, int* __restrict__ idxout,
    int* __restrict__ flagcnt, int* __restrict__ flaglist, float* __restrict__ stepb){
  __shared__ unsigned short lcb[32 * 64 * 8];
  __shared__ float lcn[128];
  int t = threadIdx.x;
  int lane = t & 63;
  int w = t >> 6;
  int col = lane & 15, hg = lane >> 4;
  int pos0 = blockIdx.x * 128 + w * 32;
  int posA = pos0 + col, posB = pos0 + 16 + col;
  const float4* Zq4 = (const float4*)Zq;
  short8x zhA[2], zlA[2], zhB[2], zlB[2];
  #pragma unroll
  for (int kc = 0; kc < 2; kc++){
    #pragma unroll
    for (int tb = 0; tb < 2; tb++){
      int pos = tb ? posB : posA;
      float4 f0 = Zq4[(size_t)(8 * kc + 2 * hg) * 65536 + pos];
      float4 f1 = Zq4[(size_t)(8 * kc + 2 * hg + 1) * 65536 + pos];
      float zv[8] = {f0.x, f0.y, f0.z, f0.w, f1.x, f1.y, f1.z, f1.w};
      union { unsigned u[4]; short8x v; } H, L;
      #pragma unroll
      for (int j = 0; j < 4; j++){
        unsigned h0 = bf16rne(zv[2 * j]);
        unsigned h1 = bf16rne(zv[2 * j + 1]);
        float hf0 = __uint_as_float(h0 << 16);
        float hf1 = __uint_as_float(h1 << 16);
        unsigned l0 = bf16rne(zv[2 * j] - hf0);
        unsigned l1 = bf16rne(zv[2 * j + 1] - hf1);
        H.u[j] = h0 | (h1 << 16);
        L.u[j] = l0 | (l1 << 16);
      }
      if (tb){ zhB[kc] = H.v; zlB[kc] = L.v; } else { zhA[kc] = H.v; zlA[kc] = L.v; }
    }
  }
  float BA = 3.0e38f, SA = 3.0e38f, BB = 3.0e38f, SBt = 3.0e38f;
  int IA = 0, IB = 0;
  for (int step = 0; step < 8; step++){
    int code0 = step * 128;
    __syncthreads();
    #pragma unroll
    for (int i = 0; i < 8; i++){
      int piece = i * 256 + t;
      int fb = piece >> 6, pl = piece & 63;
      int g = fb >> 2, kc = (fb >> 1) & 1, sp = fb & 1;
      const unsigned short* src = (sp ? cbl : cbh)
          + ((size_t)(code0 + g * 16 + (pl & 15)) << 6) + kc * 32 + ((pl >> 4) << 3);
      *(uint4*)&lcb[piece * 8] = *(const uint4*)src;
    }
    if (t < 128) lcn[t] = cbn32[code0 + t];
    __syncthreads();
    float bA = 3.0e38f, sA = 3.0e38f, bB = 3.0e38f, sB = 3.0e38f;
    int iA = 0, iB = 0;
    #pragma unroll 2
    for (int g = 0; g < 8; g++){
      const short8x* lc8 = (const short8x*)lcb;
      short8x Ah0 = lc8[(g * 4 + 0) * 64 + lane];
      short8x Al0 = lc8[(g * 4 + 1) * 64 + lane];
      short8x Ah1 = lc8[(g * 4 + 2) * 64 + lane];
      short8x Al1 = lc8[(g * 4 + 3) * 64 + lane];
      f32x4 accA = {0.f, 0.f, 0.f, 0.f};
      f32x4 accB = {0.f, 0.f, 0.f, 0.f};
      accA = __builtin_amdgcn_mfma_f32_16x16x32_bf16(Ah0, zhA[0], accA, 0, 0, 0);
      accA = __builtin_amdgcn_mfma_f32_16x16x32_bf16(Ah1, zhA[1], accA, 0, 0, 0);
      accA = __builtin_amdgcn_mfma_f32_16x16x32_bf16(Ah0, zlA[0], accA, 0, 0, 0);
      accA = __builtin_amdgcn_mfma_f32_16x16x32_bf16(Ah1, zlA[1], accA, 0, 0, 0);
      accA = __builtin_amdgcn_mfma_f32_16x16x32_bf16(Al0, zhA[0], accA, 0, 0, 0);
      accA = __builtin_amdgcn_mfma_f32_16x16x32_bf16(Al1, zhA[1], accA, 0, 0, 0);
      accB = __builtin_amdgcn_mfma_f32_16x16x32_bf16(Ah0, zhB[0], accB, 0, 0, 0);
      accB = __builtin_amdgcn_mfma_f32_16x16x32_bf16(Ah1, zhB[1], accB, 0, 0, 0);
      accB = __builtin_amdgcn_mfma_f32_16x16x32_bf16(Ah0, zlB[0], accB, 0, 0, 0);
      accB = __builtin_amdgcn_mfma_f32_16x16x32_bf16(Ah1, zlB[1], accB, 0, 0, 0);
      accB = __builtin_amdgcn_mfma_f32_16x16x32_bf16(Al0, zhB[0], accB, 0, 0, 0);
      accB = __builtin_amdgcn_mfma_f32_16x16x32_bf16(Al1, zhB[1], accB, 0, 0, 0);
      int cbase = code0 + g * 16 + 4 * hg;
      #pragma unroll
      for (int r = 0; r < 4; r++){
        float cn = lcn[g * 16 + 4 * hg + r];
        float vA = fmaf(accA[r], -2.0f, cn);
        sA = fminf(sA, fmaxf(vA, bA));
        if (vA < bA){ bA = vA; iA = cbase + r; }
        float vB = fmaf(accB[r], -2.0f, cn);
        sB = fminf(sB, fmaxf(vB, bB));
        if (vB < bB){ bB = vB; iB = cbase + r; }
      }
    }
    #pragma unroll
    for (int off = 16; off <= 32; off <<= 1){
      float ob = __shfl_xor(bA, off);
      float os = __shfl_xor(sA, off);
      int oi = __shfl_xor(iA, off);
      sA = fminf(fminf(sA, os), fmaxf(bA, ob));
      if (ob < bA){ bA = ob; iA = oi; }
      ob = __shfl_xor(bB, off);
      os = __shfl_xor(sB, off);
      oi = __shfl_xor(iB, off);
      sB = fminf(fminf(sB, os), fmaxf(bB, ob));
      if (ob < bB){ bB = ob; iB = oi; }
    }
    if (hg == 0){
      stepb[step * 65536 + posA] = bA;
      stepb[step * 65536 + posB] = bB;
    }
    if (bA < BA){ SA = fminf(BA, sA); BA = bA; IA = iA; } else SA = fminf(SA, bA);
    if (bB < BB){ SBt = fminf(BB, sB); BB = bB; IB = iB; } else SBt = fminf(SBt, bB);
  }
  if (hg == 0){
    idxout[posA] = IA;
    if (SA - BA < 1.2e-2f){
      int slot = atomicAdd(flagcnt, 1);
      flaglist[slot] = posA;
    }
    idxout[posB] = IB;
    if (SBt - BB < 1.2e-2f){
      int slot = atomicAdd(flagcnt, 1);
      flaglist[slot] = posB;
    }
  }
}

// ---------------- VQ refine: exact f64 re-rank over candidate steps only ----------------
__global__ __launch_bounds__(256) void vq_refine(const float* __restrict__ Zq, const double* __restrict__ cb64,
    const double* __restrict__ cbn64, const int* __restrict__ flagcnt, const int* __restrict__ flaglist,
    const float* __restrict__ stepb, int* __restrict__ idxout){
  int gw = (blockIdx.x * 256 + threadIdx.x) >> 6;
  int lane = threadIdx.x & 63;
  int nf = flagcnt[0];
  for (int f = gw; f < nf; f += 512){
    int pos = flaglist[f];
    float zr[64];
    #pragma unroll
    for (int q = 0; q < 16; q++){
      float4 v = ((const float4*)Zq)[q * 65536 + pos];
      zr[4 * q] = v.x; zr[4 * q + 1] = v.y; zr[4 * q + 2] = v.z; zr[4 * q + 3] = v.w;
    }
    float sb[8];
    float B = 3.0e38f;
    #pragma unroll
    for (int s = 0; s < 8; s++){ sb[s] = stepb[s * 65536 + pos]; B = fminf(B, sb[s]); }
    float lim = B + 1.2e-2f;
    double best = 1e300; int bi = 1 << 30;
    #pragma unroll
    for (int s = 0; s < 8; s++){
      if (sb[s] < lim){
        int k0 = s * 128 + 2 * lane;
        #pragma unroll
        for (int kk = 0; kk < 2; kk++){
          int k = k0 + kk;
          const double* c = cb64 + (size_t)k * 64;
          double a0 = 0, a1 = 0, a2 = 0, a3 = 0;
          #pragma unroll
          for (int d = 0; d < 64; d += 4){
            a0 = fma(c[d], (double)zr[d], a0);
            a1 = fma(c[d + 1], (double)zr[d + 1], a1);
            a2 = fma(c[d + 2], (double)zr[d + 2], a2);
            a3 = fma(c[d + 3], (double)zr[d + 3], a3);
          }
          double sc = cbn64[k] - 2.0 * ((a0 + a1) + (a2 + a3));
          if (sc < best){ best = sc; bi = k; }
        }
      }
    }
    #pragma unroll
    for (int o = 32; o > 0; o >>= 1){
      double ob = __shfl_xor(best, o);
      int oi = __shfl_xor(bi, o);
      if (ob < best || (ob == best && oi < bi)){ best = ob; bi = oi; }
    }
    if (lane == 0) idxout[pos] = bi;
  }
}

// ---------------- postq gather: out[pos][co] = bias + sum_tap P[idx[nbr]][tap][co]; fused loss ----------------
__global__ __launch_bounds__(256) void postq_gather(const float* __restrict__ P, const int* __restrict__ idxm,
    const float* __restrict__ bias, float* __restrict__ out,
    const float* __restrict__ Zq, const float* __restrict__ cb, double* __restrict__ losspart){
  int gid = blockIdx.x * 256 + threadIdx.x;
  int sp = gid & 65535;
  int co = gid >> 16;
  co = __builtin_amdgcn_readfirstlane(co);
  int xx = sp & 63, yy = (sp >> 6) & 63, n = sp >> 12;
  float acc = bias[co];
  #pragma unroll
  for (int ky = 0; ky < 3; ky++){
    int iy = yy - 1 + ky; if ((unsigned)iy >= 64u) continue;
    #pragma unroll
    for (int kx = 0; kx < 3; kx++){
      int ix = xx - 1 + kx; if ((unsigned)ix >= 64u) continue;
      int spt = (n << 12) + (iy << 6) + ix;
      int k = idxm[spt];
      acc += P[(k * 9 + (ky * 3 + kx)) * 4 + co];
    }
  }
  out[((size_t)(n * 4 + co) << 12) + (yy << 6) + xx] = acc;
  if (co == 0){
    int k = idxm[sp];
    const float4* c4 = (const float4*)(cb + (k << 6));
    double l = 0;
    #pragma unroll
    for (int q = 0; q < 16; q++){
      float4 z = ((const float4*)Zq)[q * 65536 + sp];
      float4 c = c4[q];
      float d0 = z.x - c.x, d1 = z.y - c.y, d2 = z.z - c.z, d3 = z.w - c.w;
      l += (double)d0 * d0 + (double)d1 * d1 + (double)d2 * d2 + (double)d3 * d3;
    }
    __shared__ double sb[256];
    int t = threadIdx.x;
    sb[t] = l; __syncthreads();
    for (int o = 128; o > 0; o >>= 1){
      if (t < o) sb[t] += sb[t + o];
      __syncthreads();
    }
    if (t == 0) losspart[blockIdx.x] = sb[0];
  }
}

// ---------------- transposed conv k3 s2 p1 op1, 8 co/thread, optional input-BN, fused stats ----------------
template<int CI, int CO, int IHt, int IWt, bool APPLY>
__global__ __launch_bounds__(256) void convT_cob8(const float* __restrict__ in, const float* __restrict__ w,
    const float* __restrict__ bias, const float* __restrict__ ssIn, float* __restrict__ out,
    double* __restrict__ part){
  constexpr int SB = IHt * IWt / 256;
  constexpr int COG = CO / 8;
  constexpr int P = 16 * SB;
  const int OW = IWt * 2;
  int idx = blockIdx.x * 256 + threadIdx.x;
  int ix = idx % IWt, iy = (idx / IWt) % IHt;
  int cog = (idx / (IWt * IHt)) % COG, n = idx / (IWt * IHt * COG);
  cog = __builtin_amdgcn_readfirstlane(cog);
  n   = __builtin_amdgcn_readfirstlane(n);
  float a00[8], a01[8], a10[8], a11[8];
  #pragma unroll
  for (int j = 0; j < 8; j++){ float b = bias[cog * 8 + j]; a00[j] = b; a01[j] = b; a10[j] = b; a11[j] = b; }
  bool okx = (ix + 1 < IWt), oky = (iy + 1 < IHt);
  int ixp = okx ? ix + 1 : ix, iyp = oky ? iy + 1 : iy;
  const float* ip = in + (size_t)n * CI * IHt * IWt;
  #pragma unroll 4
  for (int ci = 0; ci < CI; ci++){
    const float* p = ip + ci * IHt * IWt;
    float v00 = p[iy * IWt + ix];
    float v01 = p[iy * IWt + ixp];
    float v10 = p[iyp * IWt + ix];
    float v11 = p[iyp * IWt + ixp];
    if (APPLY){
      float sc = ssIn[ci], sh = ssIn[CI + ci];
      v00 = lrelu(fmaf(v00, sc, sh));
      v01 = lrelu(fmaf(v01, sc, sh));
      v10 = lrelu(fmaf(v10, sc, sh));
      v11 = lrelu(fmaf(v11, sc, sh));
    }
    if (!okx) v01 = 0.f;
    if (!oky) v10 = 0.f;
    if (!(okx && oky)) v11 = 0.f;
    const float* wp = w + ((size_t)ci * CO + cog * 8) * 9;
    #pragma unroll
    for (int j = 0; j < 8; j++){
      const float* q = wp + j * 9;
      a00[j] = fmaf(q[4], v00, a00[j]);
      a01[j] = fmaf(q[3], v01, a01[j]); a01[j] = fmaf(q[5], v00, a01[j]);
      a10[j] = fmaf(q[1], v10, a10[j]); a10[j] = fmaf(q[7], v00, a10[j]);
      a11[j] = fmaf(q[0], v11, a11[j]); a11[j] = fmaf(q[2], v10, a11[j]);
      a11[j] = fmaf(q[6], v01, a11[j]); a11[j] = fmaf(q[8], v00, a11[j]);
    }
  }
  float sums[8], sqs[8];
  #pragma unroll
  for (int j = 0; j < 8; j++){
    float* o = out + (((size_t)n * CO + cog * 8 + j) * (IHt * 2) + 2 * iy) * OW + 2 * ix;
    float2 r0; r0.x = a00[j]; r0.y = a01[j];
    float2 r1; r1.x = a10[j]; r1.y = a11[j];
    *(float2*)o = r0;
    *(float2*)(o + OW) = r1;
    sums[j] = (a00[j] + a01[j]) + (a10[j] + a11[j]);
    sqs[j] = (a00[j] * a00[j] + a01[j] * a01[j]) + (a10[j] * a10[j] + a11[j] * a11[j]);
  }
  __shared__ float sred[256 * 17];
  int sb = blockIdx.x % SB;
  stats_epilogue<8>(sums, sqs, part, cog * 8, P, n * SB + sb, sred);
}

// ---------------- d3: 32->3 @256x256, LDS-tiled (24 KB), shfl halo, fused bn4 + loss write ----------------
__global__ __launch_bounds__(256) void d3_tile(const float* __restrict__ F, const float* __restrict__ w,
    const float* __restrict__ bias, const float* __restrict__ ss, float* __restrict__ out,
    const double* __restrict__ losspart){
  __shared__ float st[4 * 6 * 256];
  int t = threadIdx.x;
  int xg = t & 63, r = t >> 6;
  int n = blockIdx.x >> 6, oyb = blockIdx.x & 63;
  int oy = oyb * 4 + r;
  if (blockIdx.x == 0 && t < 64){
    double s = losspart[t] + losspart[t + 64] + losspart[t + 128] + losspart[t + 192];
    #pragma unroll
    for (int o = 32; o > 0; o >>= 1) s += __shfl_xor(s, o);
    if (t == 0) out[3145728] = (float)(1.25 * s / (65536.0 * 64.0));
  }
  float acc[3][4];
  #pragma unroll
  for (int co = 0; co < 3; co++){
    float b = bias[co];
    #pragma unroll
    for (int j = 0; j < 4; j++) acc[co][j] = b;
  }
  const float* base = F + (size_t)n * 32 * 65536;
  for (int cc = 0; cc < 8; cc++){
    int cib = cc * 4;
    #pragma unroll
    for (int j = 0; j < 6; j++){
      int p = j * 256 + t;
      int cl = p / 384, rem = p - cl * 384;
      int rr = rem >> 6, xq = rem & 63;
      int g = oyb * 4 - 1 + rr;
      float4 v;
      if ((unsigned)g < 256u){
        v = *(const float4*)(base + ((size_t)(cib + cl) * 256 + g) * 256 + 4 * xq);
        float sc = ss[cib + cl], sh = ss[32 + cib + cl];
        v.x = lrelu(fmaf(v.x, sc, sh));
        v.y = lrelu(fmaf(v.y, sc, sh));
        v.z = lrelu(fmaf(v.z, sc, sh));
        v.w = lrelu(fmaf(v.w, sc, sh));
      } else {
        v.x = 0.f; v.y = 0.f; v.z = 0.f; v.w = 0.f;
      }
      *(float4*)&st[((cl * 6 + rr) << 8) | (4 * xq)] = v;
    }
    __syncthreads();
    #pragma unroll
    for (int cl = 0; cl < 4; cl++){
      #pragma unroll
      for (int ky = 0; ky < 3; ky++){
        int rr = r + ky;
        float4 A = *(const float4*)&st[((cl * 6 + rr) << 8) | (4 * xg)];
        float Lv = __shfl_up(A.w, 1);
        float Rv = __shfl_down(A.x, 1);
        float u0 = (xg == 0) ? 0.f : Lv;
        float u5 = (xg == 63) ? 0.f : Rv;
        float u[6] = {u0, A.x, A.y, A.z, A.w, u5};
        #pragma unroll
        for (int co = 0; co < 3; co++){
          const float* wp = w + ((co * 32 + cib + cl) * 9) + ky * 3;
          #pragma unroll
          for (int j = 0; j < 4; j++){
            acc[co][j] = fmaf(u[j],     wp[0], acc[co][j]);
            acc[co][j] = fmaf(u[j + 1], wp[1], acc[co][j]);
            acc[co][j] = fmaf(u[j + 2], wp[2], acc[co][j]);
          }
        }
      }
    }
    __syncthreads();
  }
  #pragma unroll
  for (int co = 0; co < 3; co++){
    float4 s0;
    s0.x = tanh_fast(acc[co][0]); s0.y = tanh_fast(acc[co][1]);
    s0.z = tanh_fast(acc[co][2]); s0.w = tanh_fast(acc[co][3]);
    float* o = out + ((size_t)(n * 3 + co) * 256 + oy) * 256 + 4 * xg;
    *(float4*)o = s0;
  }
}

// ---------------- launch ----------------
extern "C" void kernel_launch(void* const* d_in, const int* in_sizes, int n_in,
                              void* d_out, int out_size, void* d_ws, size_t ws_size,
                              hipStream_t stream){
  const float* x      = (const float*)d_in[0];
  const float* cb     = (const float*)d_in[1];
  const float* e1_w   = (const float*)d_in[2];
  const float* e1_b   = (const float*)d_in[3];
  const float* bn1_g  = (const float*)d_in[4];
  const float* bn1_b  = (const float*)d_in[5];
  const float* e2_w   = (const float*)d_in[6];
  const float* e2_b   = (const float*)d_in[7];
  const float* bn2_g  = (const float*)d_in[8];
  const float* bn2_b  = (const float*)d_in[9];
  const float* preq_w = (const float*)d_in[10];
  const float* preq_b = (const float*)d_in[11];
  const float* postq_w= (const float*)d_in[12];
  const float* postq_b= (const float*)d_in[13];
  const float* d1_w   = (const float*)d_in[14];
  const float* d1_b   = (const float*)d_in[15];
  const float* bn3_g  = (const float*)d_in[16];
  const float* bn3_b  = (const float*)d_in[17];
  const float* d2_w   = (const float*)d_in[18];
  const float* d2_b   = (const float*)d_in[19];
  const float* bn4_g  = (const float*)d_in[20];
  const float* bn4_b  = (const float*)d_in[21];
  const float* d3_w   = (const float*)d_in[22];
  const float* d3_b   = (const float*)d_in[23];
  float* out = (float*)d_out;
  char* ws = (char*)d_ws;

  double* losspart = (double*)ws;                        // 2048 B
  int*    flagcnt  = (int*)(ws + 2048);
  float*  ss       = (float*)(ws + 4096);
  double* cb64     = (double*)(ws + 8192);               // 512 KB
  double* cbn64    = (double*)(ws + 532480);             // 8 KB
  float*  cbn32    = (float*)(ws + 540672);              // 4 KB
  unsigned short* cbh = (unsigned short*)(ws + 544768);  // 128 KB
  unsigned short* cbl = (unsigned short*)(ws + 675840);  // 128 KB
  int*    flaglist = (int*)(ws + 806912);                // 256 KB
  int*    idx      = (int*)(ws + 1069056);               // 256 KB
  double* part_e1  = (double*)(ws + 1331200);            // 128 KB
  double* part_e2  = (double*)(ws + 1462272);            // 16 KB
  float*  Ptab     = (float*)(ws + 1478656);             // 147 KB (aliases part_d1; dead before d1 writes)
  double* part_d1  = (double*)(ws + 1478656);            // 64 KB
  float*  A        = (float*)(ws + 2097152);             // 16.78 MB
  float*  B        = (float*)(ws + 18874368);            // 1 MB
  float*  Zq       = (float*)(ws + 19922944);            // 16.78 MB
  double* part_d2  = (double*)(ws + 19922944);           // 512 KB, aliases Zq (dead after postq_gather)
  float*  F        = (float*)(ws + 36700160);            // 134.2 MB
  float*  stepb    = (float*)(ws + 36700160);            // 2 MB, aliases F head (dead before d2 writes F)

  float *ss1 = ss + 0, *ss2 = ss + 32, *ss3 = ss + 48, *ss4 = ss + 80;
  float* D = B;   // B dead after preq

  // encoder (e1 blocks >= 1024 run VQ/postq prep concurrently)
  e1_conv<<<1064, 256, 0, stream>>>(x, e1_w, e1_b, A, part_e1,
                                    cb, cb64, cbn64, cbn32, cbh, cbl, flagcnt, postq_w, Ptab);
  bn_red_fin<<<16, 256, 0, stream>>>(part_e1, 512, bn1_g, bn1_b, ss1, 16, 262144.0);
  e2_conv<<<1024, 256, 0, stream>>>(A, e2_w, e2_b, ss1, B, part_e2);
  bn_red_fin<<<4, 256, 0, stream>>>(part_e2, 256, bn2_g, bn2_b, ss2, 4, 65536.0);
  preq_conv<<<4096, 256, 0, stream>>>(B, preq_w, preq_b, ss2, Zq);

  // VQ
  vq_screen_mfma<<<512, 256, 0, stream>>>(Zq, cbh, cbl, cbn32, idx, flagcnt, flaglist, stepb);
  vq_refine<<<128, 256, 0, stream>>>(Zq, cb64, cbn64, flagcnt, flaglist, stepb, idx);

  // decoder (postq_gather also computes VQ loss partials; Zq dead after this)
  postq_gather<<<1024, 256, 0, stream>>>(Ptab, idx, postq_b, D, Zq, cb, losspart);
  convT_cob8<4, 16, 64, 64, false><<<512, 256, 0, stream>>>(D, d1_w, d1_b, nullptr, A, part_d1);
  bn_red_fin<<<16, 256, 0, stream>>>(part_d1, 256, bn3_g, bn3_b, ss3, 16, 262144.0);
  convT_cob8<16, 32, 128, 128, true><<<4096, 256, 0, stream>>>(A, d2_w, d2_b, ss3, F, part_d2);
  bn_red_fin<<<32, 256, 0, stream>>>(part_d2, 1024, bn4_g, bn4_b, ss4, 32, 1048576.0);
  d3_tile<<<1024, 256, 0, stream>>>(F, d3_w, d3_b, ss4, out, losspart);
}